// Round 4
// baseline (85700.232 us; speedup 1.0000x reference)
//
#include <hip/hip_runtime.h>
#include <hip/hip_bf16.h>
#include <math.h>

#define NH 6
#define DKk 256
#define DVv 512
#define HIDDIM 2048
#define TT 4096
#define NBb 2
#define MTOK (NBb*TT)   // 8192

typedef __hip_bfloat16 bf16;
typedef __attribute__((ext_vector_type(8))) short bf16x8;
typedef __attribute__((ext_vector_type(4))) float f32x4;

union FragU { bf16x8 v; uint2 u2[2]; uint4 u4; };
union BfBits { bf16 h; unsigned short s; };

__device__ inline float bflo(unsigned u) { return __uint_as_float(u << 16); }
__device__ inline float bfhi(unsigned u) { return __uint_as_float(u & 0xffff0000u); }

__device__ inline unsigned short bfbits(float f) {
    BfBits b; b.h = __float2bfloat16(f); return b.s;
}
__device__ inline uint4 pack8(float4 a, float4 b) {
    union { unsigned short s[8]; uint4 u; } r;
    r.s[0] = bfbits(a.x); r.s[1] = bfbits(a.y); r.s[2] = bfbits(a.z); r.s[3] = bfbits(a.w);
    r.s[4] = bfbits(b.x); r.s[5] = bfbits(b.y); r.s[6] = bfbits(b.z); r.s[7] = bfbits(b.w);
    return r.u;
}

// ---------------------------------------------------------------------------
// MFMA GEMM: C[m,n] = sum_k A[m,k]*B[n,k]; A: [M,K] (fp32 or bf16), B: [N,K]
// fp32. bf16 MFMA 16x16x32, fp32 accum. Tile 128x128xBK64, 4 waves (2x2),
// each wave 64x64 via 4x4 fragments. LDS XOR-swizzled (T2/G4).
// ---------------------------------------------------------------------------
template <typename TA, typename TC>
__global__ __launch_bounds__(256) void mfma_gemm_nt(const TA* __restrict__ A,
                                                    const float* __restrict__ B,
                                                    TC* __restrict__ C,
                                                    int M, int N, int K) {
    __shared__ __align__(16) short As[128 * 64];
    __shared__ __align__(16) short Bs[128 * 64];
    const int tid = threadIdx.x;
    const int lane = tid & 63;
    const int wid = tid >> 6;
    const int wr = wid >> 1, wc = wid & 1;
    const int bm = blockIdx.y * 128, bn = blockIdx.x * 128;

    const int srow = tid >> 1;            // staging row 0..127
    const int sks = (tid & 1) * 32;       // staging k-offset (elems)

    f32x4 acc[4][4];
#pragma unroll
    for (int i = 0; i < 4; ++i)
#pragma unroll
        for (int j = 0; j < 4; ++j) acc[i][j] = f32x4{0.f, 0.f, 0.f, 0.f};

    auto swzb = [](int row, int kelem) {
        return ((row * 64 + kelem) * 2) ^ ((row & 7) << 4);
    };

    uint4 ra[4], rb[4];

    auto fetch = [&](int k0) {
        if constexpr (sizeof(TA) == 2) {
            const uint4* pa = (const uint4*)(A + (size_t)(bm + srow) * K + k0 + sks);
#pragma unroll
            for (int j = 0; j < 4; ++j) ra[j] = pa[j];
        } else {
            const float4* pa = (const float4*)(A + (size_t)(bm + srow) * K + k0 + sks);
#pragma unroll
            for (int j = 0; j < 4; ++j) ra[j] = pack8(pa[2 * j], pa[2 * j + 1]);
        }
        const float4* pb = (const float4*)(B + (size_t)(bn + srow) * K + k0 + sks);
#pragma unroll
        for (int j = 0; j < 4; ++j) rb[j] = pack8(pb[2 * j], pb[2 * j + 1]);
    };

    auto store_lds = [&]() {
#pragma unroll
        for (int j = 0; j < 4; ++j) {
            int byte = swzb(srow, sks + 8 * j);
            *(uint4*)((char*)As + byte) = ra[j];
            *(uint4*)((char*)Bs + byte) = rb[j];
        }
    };

    auto rdfrag = [&](const short* Sm, int row, int kbase) {
        FragU f;
        int ko = kbase + (lane >> 4) * 4;
        f.u2[0] = *(const uint2*)((const char*)Sm + swzb(row, ko));
        f.u2[1] = *(const uint2*)((const char*)Sm + swzb(row, ko + 16));
        return f.v;
    };

    fetch(0);
    for (int k0 = 0; k0 < K; k0 += 64) {
        __syncthreads();
        store_lds();
        __syncthreads();
        if (k0 + 64 < K) fetch(k0 + 64);
#pragma unroll
        for (int kk = 0; kk < 2; ++kk) {
            bf16x8 af[4], bfr[4];
#pragma unroll
            for (int i = 0; i < 4; ++i)
                af[i] = rdfrag(As, wr * 64 + i * 16 + (lane & 15), kk * 32);
#pragma unroll
            for (int j = 0; j < 4; ++j)
                bfr[j] = rdfrag(Bs, wc * 64 + j * 16 + (lane & 15), kk * 32);
#pragma unroll
            for (int i = 0; i < 4; ++i)
#pragma unroll
                for (int j = 0; j < 4; ++j)
                    acc[i][j] = __builtin_amdgcn_mfma_f32_16x16x32_bf16(
                        af[i], bfr[j], acc[i][j], 0, 0, 0);
        }
    }

#pragma unroll
    for (int i = 0; i < 4; ++i)
#pragma unroll
        for (int j = 0; j < 4; ++j) {
            int row = bm + wr * 64 + i * 16 + (lane >> 4) * 4;
            int col = bn + wc * 64 + j * 16 + (lane & 15);
#pragma unroll
            for (int qi = 0; qi < 4; ++qi) {
                float vv = acc[i][j][qi];
                if constexpr (sizeof(TC) == 2)
                    C[(size_t)(row + qi) * N + col] = __float2bfloat16(vv);
                else
                    C[(size_t)(row + qi) * N + col] = vv;
            }
        }
}

// ---------------------------------------------------------------------------
// causal depthwise conv4 + SiLU + per-head l2norm (+scale) for q/k.
// ---------------------------------------------------------------------------
__global__ __launch_bounds__(256) void convnorm_qk(const bf16* __restrict__ pre,
                                                   const float* __restrict__ cw,
                                                   bf16* __restrict__ out,
                                                   float scale) {
    const int bth = blockIdx.x;
    const int h = bth % NH;
    const int bt = bth / NH;
    const int t = bt % TT;
    const int d = threadIdx.x;
    const int c = h * DKk + d;
    const int C = NH * DKk;
    const bf16* p = pre + (size_t)bt * C + c;

    float w0 = cw[c * 4 + 0], w1 = cw[c * 4 + 1], w2 = cw[c * 4 + 2], w3 = cw[c * 4 + 3];
    float y = w3 * __bfloat162float(p[0]);
    if (t >= 1) y = fmaf(w2, __bfloat162float(p[-(ptrdiff_t)C]), y);
    if (t >= 2) y = fmaf(w1, __bfloat162float(p[-(ptrdiff_t)(2 * C)]), y);
    if (t >= 3) y = fmaf(w0, __bfloat162float(p[-(ptrdiff_t)(3 * C)]), y);
    y = y / (1.f + expf(-y));   // SiLU

    float s = y * y;
#pragma unroll
    for (int off = 32; off >= 1; off >>= 1) s += __shfl_down(s, off, 64);
    __shared__ float red[4];
    if ((threadIdx.x & 63) == 0) red[threadIdx.x >> 6] = s;
    __syncthreads();
    float tot = (red[0] + red[1]) + (red[2] + red[3]);
    out[(size_t)bt * C + c] = __float2bfloat16(y * rsqrtf(tot + 1e-6f) * scale);
}

// ---------------------------------------------------------------------------
// causal depthwise conv4 + SiLU for v.
// ---------------------------------------------------------------------------
__global__ __launch_bounds__(256) void conv_v_kernel(const bf16* __restrict__ pre,
                                                     const float* __restrict__ cw,
                                                     bf16* __restrict__ out) {
    const int C = NH * DVv;
    int idx = blockIdx.x * 256 + threadIdx.x;
    int c = idx % C;
    int bt = idx / C;
    int t = bt % TT;
    const bf16* p = pre + (size_t)bt * C + c;
    float y = cw[c * 4 + 3] * __bfloat162float(p[0]);
    if (t >= 1) y = fmaf(cw[c * 4 + 2], __bfloat162float(p[-(ptrdiff_t)C]), y);
    if (t >= 2) y = fmaf(cw[c * 4 + 1], __bfloat162float(p[-(ptrdiff_t)(2 * C)]), y);
    if (t >= 3) y = fmaf(cw[c * 4 + 0], __bfloat162float(p[-(ptrdiff_t)(3 * C)]), y);
    out[(size_t)bt * C + c] = __float2bfloat16(y / (1.f + expf(-y)));
}

// ---------------------------------------------------------------------------
// beta = sigmoid(x@Wb.T), g = -exp(A_log)*softplus(x@Wa.T + dt_bias)
// ---------------------------------------------------------------------------
__global__ __launch_bounds__(256) void proj_ab(const float* __restrict__ x,
                                               const float* __restrict__ Wb,
                                               const float* __restrict__ Wa,
                                               const float* __restrict__ A_log,
                                               const float* __restrict__ dt_bias,
                                               float* __restrict__ beta,
                                               float* __restrict__ g) {
    const int bt = blockIdx.x;
    const int tid = threadIdx.x;
    const float* xr = x + (size_t)bt * HIDDIM;
    float accb[NH], acca[NH];
#pragma unroll
    for (int h = 0; h < NH; ++h) { accb[h] = 0.f; acca[h] = 0.f; }
    for (int k0 = tid; k0 < HIDDIM; k0 += 256) {
        float xv = xr[k0];
#pragma unroll
        for (int h = 0; h < NH; ++h) {
            accb[h] = fmaf(xv, Wb[h * HIDDIM + k0], accb[h]);
            acca[h] = fmaf(xv, Wa[h * HIDDIM + k0], acca[h]);
        }
    }
#pragma unroll
    for (int h = 0; h < NH; ++h) {
#pragma unroll
        for (int off = 32; off >= 1; off >>= 1) {
            accb[h] += __shfl_down(accb[h], off, 64);
            acca[h] += __shfl_down(acca[h], off, 64);
        }
    }
    __shared__ float redb[NH][4], reda[NH][4];
    int wv = tid >> 6;
    if ((tid & 63) == 0) {
#pragma unroll
        for (int h = 0; h < NH; ++h) { redb[h][wv] = accb[h]; reda[h][wv] = acca[h]; }
    }
    __syncthreads();
    if (tid < NH) {
        float sb = (redb[tid][0] + redb[tid][1]) + (redb[tid][2] + redb[tid][3]);
        float sa = (reda[tid][0] + reda[tid][1]) + (reda[tid][2] + reda[tid][3]);
        beta[(size_t)bt * NH + tid] = 1.f / (1.f + expf(-sb));
        float xg = sa + dt_bias[tid];
        float sp = fmaxf(xg, 0.f) + log1pf(expf(-fabsf(xg)));  // stable softplus
        g[(size_t)bt * NH + tid] = -expf(A_log[tid]) * sp;
    }
}

// ---------------------------------------------------------------------------
// Gated delta rule recurrence. Block = 1024 threads = 16 waves on ONE CU;
// wave w handles the 16-col DV slice cb = half*16 + w of (b,h). All 16 waves
// read the SAME k/q stream -> L1/L2 broadcast; 4 waves/SIMD hide latency.
// Per wave: kg=lane>>4 owns k-rows [kg*64,+64); dc=lane&15 = dv column;
// S in 64 VGPRs/thread; cross-kg reduce via shfl_xor(16,32). No barriers.
// ---------------------------------------------------------------------------
__global__ __launch_bounds__(1024) void recur_kernel3(const bf16* __restrict__ q,
                                                      const bf16* __restrict__ k,
                                                      const bf16* __restrict__ v,
                                                      const float* __restrict__ g,
                                                      const float* __restrict__ beta,
                                                      bf16* __restrict__ o) {
    const int wv = __builtin_amdgcn_readfirstlane((int)threadIdx.x >> 6); // 0..15
    const int lane = threadIdx.x & 63;
    const int half = blockIdx.x & 1;
    const int bh = blockIdx.x >> 1;
    const int h = bh % NH, b = bh / NH;
    const int cb = half * 16 + wv;     // 0..31
    const int kg = lane >> 4;
    const int dc = lane & 15;

    float S[64];
#pragma unroll
    for (int i = 0; i < 64; ++i) S[i] = 0.f;

    const size_t sQK = (size_t)NH * DKk;
    const size_t sV  = (size_t)NH * DVv;
    const bf16* kp = k + (size_t)b * TT * sQK + h * DKk + kg * 64;
    const bf16* qp = q + (size_t)b * TT * sQK + h * DKk + kg * 64;
    const bf16* vp = v + (size_t)b * TT * sV + h * DVv + cb * 16 + dc;
    const float* gp = g + (size_t)b * TT * NH + h;
    const float* bp = beta + (size_t)b * TT * NH + h;
    bf16* op = o + (size_t)b * TT * sV + h * DVv + cb * 16 + dc;

    uint4 kA[8], kB[8];
    float vA, gA, bA, vB, gB, bB;

    auto pref = [&](uint4 (&kbuf)[8], float& vv, float& gg, float& bb, int t) {
        if (t < TT) {
            const uint4* kr = (const uint4*)(kp + (size_t)t * sQK);
#pragma unroll
            for (int j = 0; j < 8; ++j) kbuf[j] = kr[j];
            vv = __bfloat162float(vp[(size_t)t * sV]);
            gg = gp[(size_t)t * NH];
            bb = bp[(size_t)t * NH];
        }
    };

    auto body = [&](const uint4 (&kc)[8], float vv, float gg, float bb, int t) {
        const uint4* qr = (const uint4*)(qp + (size_t)t * sQK);
        uint4 qc[8];
#pragma unroll
        for (int j = 0; j < 8; ++j) qc[j] = qr[j];
        float eg = expf(gg);

        // pass 1: partial k . S_old over this lane's 64 rows
        float p0 = 0.f, p1 = 0.f, p2 = 0.f, p3 = 0.f;
#pragma unroll
        for (int c = 0; c < 8; ++c) {
            uint4 u = kc[c];
            p0 = fmaf(bflo(u.x), S[c * 8 + 0], p0);
            p1 = fmaf(bfhi(u.x), S[c * 8 + 1], p1);
            p2 = fmaf(bflo(u.y), S[c * 8 + 2], p2);
            p3 = fmaf(bfhi(u.y), S[c * 8 + 3], p3);
            p0 = fmaf(bflo(u.z), S[c * 8 + 4], p0);
            p1 = fmaf(bfhi(u.z), S[c * 8 + 5], p1);
            p2 = fmaf(bflo(u.w), S[c * 8 + 6], p2);
            p3 = fmaf(bfhi(u.w), S[c * 8 + 7], p3);
        }
        float kS = (p0 + p1) + (p2 + p3);
        kS += __shfl_xor(kS, 16, 64);
        kS += __shfl_xor(kS, 32, 64);
        float vnew = vv - eg * kS;
        float bv = bb * vnew;

        // pass 2: S = S*eg + k*bv ; o_partial = q . S_new
        float o0 = 0.f, o1 = 0.f, o2 = 0.f, o3 = 0.f;
#pragma unroll
        for (int c = 0; c < 8; ++c) {
            uint4 u = kc[c], w = qc[c];
            S[c*8+0] = fmaf(S[c*8+0], eg, bflo(u.x) * bv); o0 = fmaf(bflo(w.x), S[c*8+0], o0);
            S[c*8+1] = fmaf(S[c*8+1], eg, bfhi(u.x) * bv); o1 = fmaf(bfhi(w.x), S[c*8+1], o1);
            S[c*8+2] = fmaf(S[c*8+2], eg, bflo(u.y) * bv); o2 = fmaf(bflo(w.y), S[c*8+2], o2);
            S[c*8+3] = fmaf(S[c*8+3], eg, bfhi(u.y) * bv); o3 = fmaf(bfhi(w.y), S[c*8+3], o3);
            S[c*8+4] = fmaf(S[c*8+4], eg, bflo(u.z) * bv); o0 = fmaf(bflo(w.z), S[c*8+4], o0);
            S[c*8+5] = fmaf(S[c*8+5], eg, bfhi(u.z) * bv); o1 = fmaf(bfhi(w.z), S[c*8+5], o1);
            S[c*8+6] = fmaf(S[c*8+6], eg, bflo(u.w) * bv); o2 = fmaf(bflo(w.w), S[c*8+6], o2);
            S[c*8+7] = fmaf(S[c*8+7], eg, bfhi(u.w) * bv); o3 = fmaf(bfhi(w.w), S[c*8+7], o3);
        }
        float oo = (o0 + o1) + (o2 + o3);
        oo += __shfl_xor(oo, 16, 64);
        oo += __shfl_xor(oo, 32, 64);
        if (kg == 0) op[(size_t)t * sV] = __float2bfloat16(oo);
    };

    pref(kA, vA, gA, bA, 0);
    for (int t = 0; t < TT; t += 2) {
        pref(kB, vB, gB, bB, t + 1);
        body(kA, vA, gA, bA, t);
        pref(kA, vA, gA, bA, t + 2);
        body(kB, vB, gB, bB, t + 1);
    }
}

// ---------------------------------------------------------------------------
// per-head RMSNorm (eps 1e-5) * norm_w, then * silu(gate). In-place (bf16).
// ---------------------------------------------------------------------------
__global__ __launch_bounds__(256) void rmsgate_kernel(bf16* __restrict__ o,
                                                      const bf16* __restrict__ gate,
                                                      const float* __restrict__ norm_w) {
    const int bhead = blockIdx.x;
    const int d = threadIdx.x;
    bf16* op = o + (size_t)bhead * DVv;
    const bf16* gp = gate + (size_t)bhead * DVv;
    float x0 = __bfloat162float(op[d]), x1 = __bfloat162float(op[d + 256]);
    float s = x0 * x0 + x1 * x1;
#pragma unroll
    for (int off = 32; off >= 1; off >>= 1) s += __shfl_down(s, off, 64);
    __shared__ float red[4];
    if ((threadIdx.x & 63) == 0) red[threadIdx.x >> 6] = s;
    __syncthreads();
    float tot = (red[0] + red[1]) + (red[2] + red[3]);
    float r = rsqrtf(tot * (1.f / DVv) + 1e-5f);
    float g0 = __bfloat162float(gp[d]), g1 = __bfloat162float(gp[d + 256]);
    g0 = g0 / (1.f + expf(-g0));
    g1 = g1 / (1.f + expf(-g1));
    op[d]       = __float2bfloat16(x0 * r * norm_w[d] * g0);
    op[d + 256] = __float2bfloat16(x1 * r * norm_w[d + 256] * g1);
}

__global__ void fill_kernel(float* p, int n, float v) {
    int i = blockIdx.x * 256 + threadIdx.x;
    if (i < n) p[i] = v;
}

// ---------------------------------------------------------------------------
extern "C" void kernel_launch(void* const* d_in, const int* in_sizes, int n_in,
                              void* d_out, int out_size, void* d_ws, size_t ws_size,
                              hipStream_t stream) {
    const float* x       = (const float*)d_in[0];
    const float* Wq      = (const float*)d_in[1];
    const float* Wk      = (const float*)d_in[2];
    const float* Wv      = (const float*)d_in[3];
    const float* Wb      = (const float*)d_in[4];
    const float* Wa      = (const float*)d_in[5];
    const float* A_log   = (const float*)d_in[6];
    const float* dt_bias = (const float*)d_in[7];
    const float* cwq     = (const float*)d_in[8];
    const float* cwk     = (const float*)d_in[9];
    const float* cwv     = (const float*)d_in[10];
    const float* Wg      = (const float*)d_in[11];
    const float* norm_w  = (const float*)d_in[12];
    const float* Wo      = (const float*)d_in[13];
    float* out = (float*)d_out;

    // d_out doubles as scratch for q/k (bf16, 50.3MB <= 67.1MB), dead before
    // the final GEMM overwrites d_out with fp32 results.
    bf16* qb = (bf16*)d_out;                         // [8192,1536] bf16
    bf16* kb = qb + (size_t)MTOK * 1536;             // [8192,1536] bf16

    // ws: A = {preQ|preK|v|gate}, B = {preV|o}, beta/g fp32.
    const size_t elemsA = (size_t)MTOK * 3072;
    const size_t elemsB = (size_t)MTOK * 3072;
    bf16* wsA   = (bf16*)d_ws;
    bf16* wsB   = wsA + elemsA;
    float* betab = (float*)(wsB + elemsB);
    float* gb    = betab + (size_t)MTOK * NH;
    size_t need = (elemsA + elemsB) * sizeof(bf16) + 2 * (size_t)MTOK * NH * sizeof(float);
    if (ws_size < need) {
        fill_kernel<<<(out_size + 255) / 256, 256, 0, stream>>>(out, out_size, 1e9f);
        return;
    }

    dim3 blk(256);
    // q projection -> conv+silu+l2norm (*DK^-0.5)
    mfma_gemm_nt<float, bf16><<<dim3(12, 64), blk, 0, stream>>>(x, Wq, wsA, MTOK, 1536, HIDDIM);
    convnorm_qk<<<MTOK * NH, dim3(DKk), 0, stream>>>(wsA, cwq, qb, 0.0625f);
    // k projection -> conv+silu+l2norm
    mfma_gemm_nt<float, bf16><<<dim3(12, 64), blk, 0, stream>>>(x, Wk, wsA, MTOK, 1536, HIDDIM);
    convnorm_qk<<<MTOK * NH, dim3(DKk), 0, stream>>>(wsA, cwk, kb, 1.0f);
    // v projection (into B) -> conv+silu (into A)
    mfma_gemm_nt<float, bf16><<<dim3(24, 64), blk, 0, stream>>>(x, Wv, wsB, MTOK, 3072, HIDDIM);
    conv_v_kernel<<<(MTOK * 3072) / 256, blk, 0, stream>>>(wsB, cwv, wsA);
    // beta / g
    proj_ab<<<MTOK, blk, 0, stream>>>(x, Wb, Wa, A_log, dt_bias, betab, gb);
    // recurrence: q,k (d_out), v (A) -> o (B). 24 blocks x 16 waves.
    recur_kernel3<<<NBb * NH * 2, dim3(1024), 0, stream>>>(qb, kb, wsA, gb, betab, wsB);
    // gate projection into A (v dead)
    mfma_gemm_nt<float, bf16><<<dim3(24, 64), blk, 0, stream>>>(x, Wg, wsA, MTOK, 3072, HIDDIM);
    // rmsnorm + silu(gate), in place on o (B)
    rmsgate_kernel<<<MTOK * NH, blk, 0, stream>>>(wsB, wsA, norm_w);
    // output projection: o (bf16, B) x Wo (fp32) -> d_out fp32
    mfma_gemm_nt<bf16, float><<<dim3(16, 64), blk, 0, stream>>>(wsB, Wo, out, MTOK, 2048, 3072);
}

// Round 5
// 6945.238 us; speedup vs baseline: 12.3394x; 12.3394x over previous
//
#include <hip/hip_runtime.h>
#include <hip/hip_bf16.h>
#include <math.h>

#define NH 6
#define DKk 256
#define DVv 512
#define HIDDIM 2048
#define TT 4096
#define NBb 2
#define MTOK (NBb*TT)   // 8192

typedef __hip_bfloat16 bf16;
typedef __attribute__((ext_vector_type(8))) short bf16x8;
typedef __attribute__((ext_vector_type(4))) float f32x4;

union FragU { bf16x8 v; uint2 u2[2]; uint4 u4; };
union BfBits { bf16 h; unsigned short s; };

__device__ inline float bflo(unsigned u) { return __uint_as_float(u << 16); }
__device__ inline float bfhi(unsigned u) { return __uint_as_float(u & 0xffff0000u); }

__device__ inline unsigned short bfbits(float f) {
    BfBits b; b.h = __float2bfloat16(f); return b.s;
}
__device__ inline uint4 pack8(float4 a, float4 b) {
    union { unsigned short s[8]; uint4 u; } r;
    r.s[0] = bfbits(a.x); r.s[1] = bfbits(a.y); r.s[2] = bfbits(a.z); r.s[3] = bfbits(a.w);
    r.s[4] = bfbits(b.x); r.s[5] = bfbits(b.y); r.s[6] = bfbits(b.z); r.s[7] = bfbits(b.w);
    return r.u;
}

// ---------------------------------------------------------------------------
// MFMA GEMM: C[m,n] = sum_k A[m,k]*B[n,k]; A: [M,K] (fp32 or bf16), B: [N,K]
// fp32. bf16 MFMA 16x16x32, fp32 accum. Tile 128x128xBK64, 4 waves (2x2),
// each wave 64x64 via 4x4 fragments. LDS XOR-swizzled (T2/G4).
// ---------------------------------------------------------------------------
template <typename TA, typename TC>
__global__ __launch_bounds__(256) void mfma_gemm_nt(const TA* __restrict__ A,
                                                    const float* __restrict__ B,
                                                    TC* __restrict__ C,
                                                    int M, int N, int K) {
    __shared__ __align__(16) short As[128 * 64];
    __shared__ __align__(16) short Bs[128 * 64];
    const int tid = threadIdx.x;
    const int lane = tid & 63;
    const int wid = tid >> 6;
    const int wr = wid >> 1, wc = wid & 1;
    const int bm = blockIdx.y * 128, bn = blockIdx.x * 128;

    const int srow = tid >> 1;            // staging row 0..127
    const int sks = (tid & 1) * 32;       // staging k-offset (elems)

    f32x4 acc[4][4];
#pragma unroll
    for (int i = 0; i < 4; ++i)
#pragma unroll
        for (int j = 0; j < 4; ++j) acc[i][j] = f32x4{0.f, 0.f, 0.f, 0.f};

    auto swzb = [](int row, int kelem) {
        return ((row * 64 + kelem) * 2) ^ ((row & 7) << 4);
    };

    uint4 ra[4], rb[4];

    auto fetch = [&](int k0) {
        if constexpr (sizeof(TA) == 2) {
            const uint4* pa = (const uint4*)(A + (size_t)(bm + srow) * K + k0 + sks);
#pragma unroll
            for (int j = 0; j < 4; ++j) ra[j] = pa[j];
        } else {
            const float4* pa = (const float4*)(A + (size_t)(bm + srow) * K + k0 + sks);
#pragma unroll
            for (int j = 0; j < 4; ++j) ra[j] = pack8(pa[2 * j], pa[2 * j + 1]);
        }
        const float4* pb = (const float4*)(B + (size_t)(bn + srow) * K + k0 + sks);
#pragma unroll
        for (int j = 0; j < 4; ++j) rb[j] = pack8(pb[2 * j], pb[2 * j + 1]);
    };

    auto store_lds = [&]() {
#pragma unroll
        for (int j = 0; j < 4; ++j) {
            int byte = swzb(srow, sks + 8 * j);
            *(uint4*)((char*)As + byte) = ra[j];
            *(uint4*)((char*)Bs + byte) = rb[j];
        }
    };

    auto rdfrag = [&](const short* Sm, int row, int kbase) {
        FragU f;
        int ko = kbase + (lane >> 4) * 4;
        f.u2[0] = *(const uint2*)((const char*)Sm + swzb(row, ko));
        f.u2[1] = *(const uint2*)((const char*)Sm + swzb(row, ko + 16));
        return f.v;
    };

    fetch(0);
    for (int k0 = 0; k0 < K; k0 += 64) {
        __syncthreads();
        store_lds();
        __syncthreads();
        if (k0 + 64 < K) fetch(k0 + 64);
#pragma unroll
        for (int kk = 0; kk < 2; ++kk) {
            bf16x8 af[4], bfr[4];
#pragma unroll
            for (int i = 0; i < 4; ++i)
                af[i] = rdfrag(As, wr * 64 + i * 16 + (lane & 15), kk * 32);
#pragma unroll
            for (int j = 0; j < 4; ++j)
                bfr[j] = rdfrag(Bs, wc * 64 + j * 16 + (lane & 15), kk * 32);
#pragma unroll
            for (int i = 0; i < 4; ++i)
#pragma unroll
                for (int j = 0; j < 4; ++j)
                    acc[i][j] = __builtin_amdgcn_mfma_f32_16x16x32_bf16(
                        af[i], bfr[j], acc[i][j], 0, 0, 0);
        }
    }

#pragma unroll
    for (int i = 0; i < 4; ++i)
#pragma unroll
        for (int j = 0; j < 4; ++j) {
            int row = bm + wr * 64 + i * 16 + (lane >> 4) * 4;
            int col = bn + wc * 64 + j * 16 + (lane & 15);
#pragma unroll
            for (int qi = 0; qi < 4; ++qi) {
                float vv = acc[i][j][qi];
                if constexpr (sizeof(TC) == 2)
                    C[(size_t)(row + qi) * N + col] = __float2bfloat16(vv);
                else
                    C[(size_t)(row + qi) * N + col] = vv;
            }
        }
}

// ---------------------------------------------------------------------------
// causal depthwise conv4 + SiLU + per-head l2norm (+scale) for q/k.
// ---------------------------------------------------------------------------
__global__ __launch_bounds__(256) void convnorm_qk(const bf16* __restrict__ pre,
                                                   const float* __restrict__ cw,
                                                   bf16* __restrict__ out,
                                                   float scale) {
    const int bth = blockIdx.x;
    const int h = bth % NH;
    const int bt = bth / NH;
    const int t = bt % TT;
    const int d = threadIdx.x;
    const int c = h * DKk + d;
    const int C = NH * DKk;
    const bf16* p = pre + (size_t)bt * C + c;

    float w0 = cw[c * 4 + 0], w1 = cw[c * 4 + 1], w2 = cw[c * 4 + 2], w3 = cw[c * 4 + 3];
    float y = w3 * __bfloat162float(p[0]);
    if (t >= 1) y = fmaf(w2, __bfloat162float(p[-(ptrdiff_t)C]), y);
    if (t >= 2) y = fmaf(w1, __bfloat162float(p[-(ptrdiff_t)(2 * C)]), y);
    if (t >= 3) y = fmaf(w0, __bfloat162float(p[-(ptrdiff_t)(3 * C)]), y);
    y = y / (1.f + expf(-y));   // SiLU

    float s = y * y;
#pragma unroll
    for (int off = 32; off >= 1; off >>= 1) s += __shfl_down(s, off, 64);
    __shared__ float red[4];
    if ((threadIdx.x & 63) == 0) red[threadIdx.x >> 6] = s;
    __syncthreads();
    float tot = (red[0] + red[1]) + (red[2] + red[3]);
    out[(size_t)bt * C + c] = __float2bfloat16(y * rsqrtf(tot + 1e-6f) * scale);
}

// ---------------------------------------------------------------------------
// causal depthwise conv4 + SiLU for v.
// ---------------------------------------------------------------------------
__global__ __launch_bounds__(256) void conv_v_kernel(const bf16* __restrict__ pre,
                                                     const float* __restrict__ cw,
                                                     bf16* __restrict__ out) {
    const int C = NH * DVv;
    int idx = blockIdx.x * 256 + threadIdx.x;
    int c = idx % C;
    int bt = idx / C;
    int t = bt % TT;
    const bf16* p = pre + (size_t)bt * C + c;
    float y = cw[c * 4 + 3] * __bfloat162float(p[0]);
    if (t >= 1) y = fmaf(cw[c * 4 + 2], __bfloat162float(p[-(ptrdiff_t)C]), y);
    if (t >= 2) y = fmaf(cw[c * 4 + 1], __bfloat162float(p[-(ptrdiff_t)(2 * C)]), y);
    if (t >= 3) y = fmaf(cw[c * 4 + 0], __bfloat162float(p[-(ptrdiff_t)(3 * C)]), y);
    out[(size_t)bt * C + c] = __float2bfloat16(y / (1.f + expf(-y)));
}

// ---------------------------------------------------------------------------
// beta = sigmoid(x@Wb.T), g = -exp(A_log)*softplus(x@Wa.T + dt_bias)
// ---------------------------------------------------------------------------
__global__ __launch_bounds__(256) void proj_ab(const float* __restrict__ x,
                                               const float* __restrict__ Wb,
                                               const float* __restrict__ Wa,
                                               const float* __restrict__ A_log,
                                               const float* __restrict__ dt_bias,
                                               float* __restrict__ beta,
                                               float* __restrict__ g) {
    const int bt = blockIdx.x;
    const int tid = threadIdx.x;
    const float* xr = x + (size_t)bt * HIDDIM;
    float accb[NH], acca[NH];
#pragma unroll
    for (int h = 0; h < NH; ++h) { accb[h] = 0.f; acca[h] = 0.f; }
    for (int k0 = tid; k0 < HIDDIM; k0 += 256) {
        float xv = xr[k0];
#pragma unroll
        for (int h = 0; h < NH; ++h) {
            accb[h] = fmaf(xv, Wb[h * HIDDIM + k0], accb[h]);
            acca[h] = fmaf(xv, Wa[h * HIDDIM + k0], acca[h]);
        }
    }
#pragma unroll
    for (int h = 0; h < NH; ++h) {
#pragma unroll
        for (int off = 32; off >= 1; off >>= 1) {
            accb[h] += __shfl_down(accb[h], off, 64);
            acca[h] += __shfl_down(acca[h], off, 64);
        }
    }
    __shared__ float redb[NH][4], reda[NH][4];
    int wv = tid >> 6;
    if ((tid & 63) == 0) {
#pragma unroll
        for (int h = 0; h < NH; ++h) { redb[h][wv] = accb[h]; reda[h][wv] = acca[h]; }
    }
    __syncthreads();
    if (tid < NH) {
        float sb = (redb[tid][0] + redb[tid][1]) + (redb[tid][2] + redb[tid][3]);
        float sa = (reda[tid][0] + reda[tid][1]) + (reda[tid][2] + reda[tid][3]);
        beta[(size_t)bt * NH + tid] = 1.f / (1.f + expf(-sb));
        float xg = sa + dt_bias[tid];
        float sp = fmaxf(xg, 0.f) + log1pf(expf(-fabsf(xg)));  // stable softplus
        g[(size_t)bt * NH + tid] = -expf(A_log[tid]) * sp;
    }
}

// ---------------------------------------------------------------------------
// Gated delta rule recurrence, single-wave blocks (no barriers, no LDS tile).
// Block = 1 wave handles (b,h, 16-col slice of DV). kg=lane>>4 owns k-rows
// [kg*64,+64); dc=lane&15 = dv column. S in 64 VGPRs/thread.
// BOTH k and q double-buffer-prefetched; shuffle latency hidden by the
// algebraic split  o = q.(S*eg) + (q.k)*bv.
// ---------------------------------------------------------------------------
__global__ __launch_bounds__(64, 1) void recur_kernel4(const bf16* __restrict__ q,
                                                       const bf16* __restrict__ k,
                                                       const bf16* __restrict__ v,
                                                       const float* __restrict__ g,
                                                       const float* __restrict__ beta,
                                                       bf16* __restrict__ o) {
    const int NCB = DVv / 16;   // 32
    const int cb = blockIdx.x % NCB;
    const int bh = blockIdx.x / NCB;
    const int h = bh % NH, b = bh / NH;
    const int lane = threadIdx.x;
    const int kg = lane >> 4;
    const int dc = lane & 15;

    float S[64];
#pragma unroll
    for (int i = 0; i < 64; ++i) S[i] = 0.f;

    const size_t sQK = (size_t)NH * DKk;
    const size_t sV  = (size_t)NH * DVv;
    const bf16* kp = k + (size_t)b * TT * sQK + h * DKk + kg * 64;
    const bf16* qp = q + (size_t)b * TT * sQK + h * DKk + kg * 64;
    const bf16* vp = v + (size_t)b * TT * sV + h * DVv + cb * 16 + dc;
    const float* gp = g + (size_t)b * TT * NH + h;
    const float* bp = beta + (size_t)b * TT * NH + h;
    bf16* op = o + (size_t)b * TT * sV + h * DVv + cb * 16 + dc;

    uint4 kA[8], kB[8], qA[8], qB[8];
    float vA, gA, bA, vB, gB, bB;

    auto pref = [&](uint4 (&kbuf)[8], uint4 (&qbuf)[8],
                    float& vv, float& gg, float& bb, int t) {
        if (t < TT) {
            const uint4* kr = (const uint4*)(kp + (size_t)t * sQK);
            const uint4* qr = (const uint4*)(qp + (size_t)t * sQK);
#pragma unroll
            for (int j = 0; j < 8; ++j) kbuf[j] = kr[j];
#pragma unroll
            for (int j = 0; j < 8; ++j) qbuf[j] = qr[j];
            vv = __bfloat162float(vp[(size_t)t * sV]);
            gg = gp[(size_t)t * NH];
            bb = bp[(size_t)t * NH];
        }
    };

    auto body = [&](const uint4 (&kc)[8], const uint4 (&qc)[8],
                    float vv, float gg, float bb, int t) {
        float eg = expf(gg);

        // pass 1: partial k . S_old over this lane's 64 rows
        float p0 = 0.f, p1 = 0.f, p2 = 0.f, p3 = 0.f;
#pragma unroll
        for (int c = 0; c < 8; ++c) {
            uint4 u = kc[c];
            p0 = fmaf(bflo(u.x), S[c * 8 + 0], p0);
            p1 = fmaf(bfhi(u.x), S[c * 8 + 1], p1);
            p2 = fmaf(bflo(u.y), S[c * 8 + 2], p2);
            p3 = fmaf(bfhi(u.y), S[c * 8 + 3], p3);
            p0 = fmaf(bflo(u.z), S[c * 8 + 4], p0);
            p1 = fmaf(bfhi(u.z), S[c * 8 + 5], p1);
            p2 = fmaf(bflo(u.w), S[c * 8 + 6], p2);
            p3 = fmaf(bfhi(u.w), S[c * 8 + 7], p3);
        }
        float r = (p0 + p1) + (p2 + p3);
        float r16 = __shfl_xor(r, 16, 64);      // LDS latency hidden by:

        // in-place decay (independent of the reduction)
#pragma unroll
        for (int i = 0; i < 64; ++i) S[i] *= eg;

        float s2 = r + r16;
        float r32 = __shfl_xor(s2, 32, 64);     // hidden by qs/qk below:

        // qs = q . (S*eg), qk = q . k  (both independent of kS)
        float a0 = 0.f, a1 = 0.f, a2 = 0.f, a3 = 0.f;
        float c0 = 0.f, c1 = 0.f, c2 = 0.f, c3 = 0.f;
#pragma unroll
        for (int c = 0; c < 8; ++c) {
            uint4 u = kc[c], w = qc[c];
            float q0 = bflo(w.x), q1 = bfhi(w.x), q2 = bflo(w.y), q3 = bfhi(w.y);
            float q4 = bflo(w.z), q5 = bfhi(w.z), q6 = bflo(w.w), q7 = bfhi(w.w);
            a0 = fmaf(q0, S[c * 8 + 0], a0); c0 = fmaf(q0, bflo(u.x), c0);
            a1 = fmaf(q1, S[c * 8 + 1], a1); c1 = fmaf(q1, bfhi(u.x), c1);
            a2 = fmaf(q2, S[c * 8 + 2], a2); c2 = fmaf(q2, bflo(u.y), c2);
            a3 = fmaf(q3, S[c * 8 + 3], a3); c3 = fmaf(q3, bfhi(u.y), c3);
            a0 = fmaf(q4, S[c * 8 + 4], a0); c0 = fmaf(q4, bflo(u.z), c0);
            a1 = fmaf(q5, S[c * 8 + 5], a1); c1 = fmaf(q5, bfhi(u.z), c1);
            a2 = fmaf(q6, S[c * 8 + 6], a2); c2 = fmaf(q6, bflo(u.w), c2);
            a3 = fmaf(q7, S[c * 8 + 7], a3); c3 = fmaf(q7, bfhi(u.w), c3);
        }
        float qs = (a0 + a1) + (a2 + a3);
        float qk = (c0 + c1) + (c2 + c3);

        float kS = s2 + r32;
        float vnew = vv - eg * kS;
        float bv = bb * vnew;

        // S_new = S*eg + k*bv (S already decayed in place)
#pragma unroll
        for (int c = 0; c < 8; ++c) {
            uint4 u = kc[c];
            S[c*8+0] = fmaf(bflo(u.x), bv, S[c*8+0]);
            S[c*8+1] = fmaf(bfhi(u.x), bv, S[c*8+1]);
            S[c*8+2] = fmaf(bflo(u.y), bv, S[c*8+2]);
            S[c*8+3] = fmaf(bfhi(u.y), bv, S[c*8+3]);
            S[c*8+4] = fmaf(bflo(u.z), bv, S[c*8+4]);
            S[c*8+5] = fmaf(bfhi(u.z), bv, S[c*8+5]);
            S[c*8+6] = fmaf(bflo(u.w), bv, S[c*8+6]);
            S[c*8+7] = fmaf(bfhi(u.w), bv, S[c*8+7]);
        }

        // o = qs + bv*qk, reduce across kg groups (off the S critical path)
        float oo = fmaf(bv, qk, qs);
        oo += __shfl_xor(oo, 16, 64);
        oo += __shfl_xor(oo, 32, 64);
        if (kg == 0) op[(size_t)t * sV] = __float2bfloat16(oo);
    };

    pref(kA, qA, vA, gA, bA, 0);
    for (int t = 0; t < TT; t += 2) {
        pref(kB, qB, vB, gB, bB, t + 1);
        body(kA, qA, vA, gA, bA, t);
        pref(kA, qA, vA, gA, bA, t + 2);
        body(kB, qB, vB, gB, bB, t + 1);
    }
}

// ---------------------------------------------------------------------------
// per-head RMSNorm (eps 1e-5) * norm_w, then * silu(gate). In-place (bf16).
// ---------------------------------------------------------------------------
__global__ __launch_bounds__(256) void rmsgate_kernel(bf16* __restrict__ o,
                                                      const bf16* __restrict__ gate,
                                                      const float* __restrict__ norm_w) {
    const int bhead = blockIdx.x;
    const int d = threadIdx.x;
    bf16* op = o + (size_t)bhead * DVv;
    const bf16* gp = gate + (size_t)bhead * DVv;
    float x0 = __bfloat162float(op[d]), x1 = __bfloat162float(op[d + 256]);
    float s = x0 * x0 + x1 * x1;
#pragma unroll
    for (int off = 32; off >= 1; off >>= 1) s += __shfl_down(s, off, 64);
    __shared__ float red[4];
    if ((threadIdx.x & 63) == 0) red[threadIdx.x >> 6] = s;
    __syncthreads();
    float tot = (red[0] + red[1]) + (red[2] + red[3]);
    float r = rsqrtf(tot * (1.f / DVv) + 1e-5f);
    float g0 = __bfloat162float(gp[d]), g1 = __bfloat162float(gp[d + 256]);
    g0 = g0 / (1.f + expf(-g0));
    g1 = g1 / (1.f + expf(-g1));
    op[d]       = __float2bfloat16(x0 * r * norm_w[d] * g0);
    op[d + 256] = __float2bfloat16(x1 * r * norm_w[d + 256] * g1);
}

__global__ void fill_kernel(float* p, int n, float v) {
    int i = blockIdx.x * 256 + threadIdx.x;
    if (i < n) p[i] = v;
}

// ---------------------------------------------------------------------------
extern "C" void kernel_launch(void* const* d_in, const int* in_sizes, int n_in,
                              void* d_out, int out_size, void* d_ws, size_t ws_size,
                              hipStream_t stream) {
    const float* x       = (const float*)d_in[0];
    const float* Wq      = (const float*)d_in[1];
    const float* Wk      = (const float*)d_in[2];
    const float* Wv      = (const float*)d_in[3];
    const float* Wb      = (const float*)d_in[4];
    const float* Wa      = (const float*)d_in[5];
    const float* A_log   = (const float*)d_in[6];
    const float* dt_bias = (const float*)d_in[7];
    const float* cwq     = (const float*)d_in[8];
    const float* cwk     = (const float*)d_in[9];
    const float* cwv     = (const float*)d_in[10];
    const float* Wg      = (const float*)d_in[11];
    const float* norm_w  = (const float*)d_in[12];
    const float* Wo      = (const float*)d_in[13];
    float* out = (float*)d_out;

    // d_out doubles as scratch for q/k (bf16, 50.3MB <= 67.1MB), dead before
    // the final GEMM overwrites d_out with fp32 results.
    bf16* qb = (bf16*)d_out;                         // [8192,1536] bf16
    bf16* kb = qb + (size_t)MTOK * 1536;             // [8192,1536] bf16

    // ws: A = {preQ|preK|v|gate}, B = {preV|o}, beta/g fp32.
    const size_t elemsA = (size_t)MTOK * 3072;
    const size_t elemsB = (size_t)MTOK * 3072;
    bf16* wsA   = (bf16*)d_ws;
    bf16* wsB   = wsA + elemsA;
    float* betab = (float*)(wsB + elemsB);
    float* gb    = betab + (size_t)MTOK * NH;
    size_t need = (elemsA + elemsB) * sizeof(bf16) + 2 * (size_t)MTOK * NH * sizeof(float);
    if (ws_size < need) {
        fill_kernel<<<(out_size + 255) / 256, 256, 0, stream>>>(out, out_size, 1e9f);
        return;
    }

    dim3 blk(256);
    // q projection -> conv+silu+l2norm (*DK^-0.5)
    mfma_gemm_nt<float, bf16><<<dim3(12, 64), blk, 0, stream>>>(x, Wq, wsA, MTOK, 1536, HIDDIM);
    convnorm_qk<<<MTOK * NH, dim3(DKk), 0, stream>>>(wsA, cwq, qb, 0.0625f);
    // k projection -> conv+silu+l2norm
    mfma_gemm_nt<float, bf16><<<dim3(12, 64), blk, 0, stream>>>(x, Wk, wsA, MTOK, 1536, HIDDIM);
    convnorm_qk<<<MTOK * NH, dim3(DKk), 0, stream>>>(wsA, cwk, kb, 1.0f);
    // v projection (into B) -> conv+silu (into A)
    mfma_gemm_nt<float, bf16><<<dim3(24, 64), blk, 0, stream>>>(x, Wv, wsB, MTOK, 3072, HIDDIM);
    conv_v_kernel<<<(MTOK * 3072) / 256, blk, 0, stream>>>(wsB, cwv, wsA);
    // beta / g
    proj_ab<<<MTOK, blk, 0, stream>>>(x, Wb, Wa, A_log, dt_bias, betab, gb);
    // recurrence: q,k (d_out), v (A) -> o (B). 384 blocks x 1 wave.
    recur_kernel4<<<NBb * NH * (DVv / 16), dim3(64), 0, stream>>>(qb, kb, wsA, gb, betab, wsB);
    // gate projection into A (v dead)
    mfma_gemm_nt<float, bf16><<<dim3(24, 64), blk, 0, stream>>>(x, Wg, wsA, MTOK, 3072, HIDDIM);
    // rmsnorm + silu(gate), in place on o (B)
    rmsgate_kernel<<<MTOK * NH, blk, 0, stream>>>(wsB, wsA, norm_w);
    // output projection: o (bf16, B) x Wo (fp32) -> d_out fp32
    mfma_gemm_nt<bf16, float><<<dim3(16, 64), blk, 0, stream>>>(wsB, Wo, out, MTOK, 2048, 3072);
}

// Round 7
// 3995.575 us; speedup vs baseline: 21.4488x; 1.7382x over previous
//
#include <hip/hip_runtime.h>
#include <hip/hip_bf16.h>
#include <math.h>

#define NH 6
#define DKk 256
#define DVv 512
#define HIDDIM 2048
#define TT 4096
#define NBb 2
#define MTOK (NBb*TT)   // 8192
#define CH 64
#define NCH (TT/CH)     // 64 chunks per sequence
#define SCLN 136

typedef __hip_bfloat16 bf16;
typedef __attribute__((ext_vector_type(8))) short bf16x8;
typedef __attribute__((ext_vector_type(4))) float f32x4;

union FragU { bf16x8 v; uint2 u2[2]; uint4 u4; };
union BfBits { bf16 h; unsigned short s; };
union U4S8 { uint4 u; unsigned short s[8]; };

__device__ inline float bflo(unsigned u) { return __uint_as_float(u << 16); }
__device__ inline float bfhi(unsigned u) { return __uint_as_float(u & 0xffff0000u); }
__device__ inline unsigned short bfbits(float f) {
    BfBits b; b.h = __float2bfloat16(f); return b.s;
}
__device__ inline float bf2f(unsigned short s) { return __uint_as_float(((unsigned)s) << 16); }
__device__ inline uint4 pack8(float4 a, float4 b) {
    U4S8 r;
    r.s[0] = bfbits(a.x); r.s[1] = bfbits(a.y); r.s[2] = bfbits(a.z); r.s[3] = bfbits(a.w);
    r.s[4] = bfbits(b.x); r.s[5] = bfbits(b.y); r.s[6] = bfbits(b.z); r.s[7] = bfbits(b.w);
    return r.u;
}
__device__ inline uint2 packh4(float a, float b, float c, float d) {
    union { unsigned short s[4]; uint2 u; } r;
    r.s[0] = bfbits(a); r.s[1] = bfbits(b); r.s[2] = bfbits(c); r.s[3] = bfbits(d);
    return r.u;
}

// B/A-fragment loaders. k-pattern: (lane>>4)*4 + {0..3} and +16..19 (consistent
// across ALL operands -> permutation-invariant over K).
__device__ inline bf16x8 gfrag(const bf16* base, size_t stride, int n0, int k0) {
    int lane = threadIdx.x & 63;
    const bf16* p = base + (size_t)(n0 + (lane & 15)) * stride + k0 + ((lane >> 4) * 4);
    FragU f; f.u2[0] = *(const uint2*)p; f.u2[1] = *(const uint2*)(p + 16);
    return f.v;
}
// LDS tile stride 256 elems, XOR-swizzled by ((row&7)<<4) on byte offset
__device__ inline bf16x8 lfrag256(const short* sh, int n0, int k0) {
    int lane = threadIdx.x & 63;
    int r = n0 + (lane & 15);
    int c = k0 + ((lane >> 4) * 4);
    FragU f;
    f.u2[0] = *(const uint2*)((const char*)sh + (((r * 256 + c) * 2) ^ ((r & 7) << 4)));
    f.u2[1] = *(const uint2*)((const char*)sh + (((r * 256 + c + 16) * 2) ^ ((r & 7) << 4)));
    return f.v;
}
// LDS tile stride 64 elems, swizzled
__device__ inline bf16x8 lfrag64(const short* sh, int n0, int k0) {
    int lane = threadIdx.x & 63;
    int r = n0 + (lane & 15);
    int c = k0 + ((lane >> 4) * 4);
    FragU f;
    f.u2[0] = *(const uint2*)((const char*)sh + (((r * 64 + c) * 2) ^ ((r & 7) << 4)));
    f.u2[1] = *(const uint2*)((const char*)sh + (((r * 64 + c + 16) * 2) ^ ((r & 7) << 4)));
    return f.v;
}
// LDS tile stride 72 elems (padded), no swizzle
__device__ inline bf16x8 lfrag72(const short* sh, int n0, int k0) {
    int lane = threadIdx.x & 63;
    int r = n0 + (lane & 15);
    int c = k0 + ((lane >> 4) * 4);
    FragU f;
    f.u2[0] = *(const uint2*)((const char*)sh + (r * 72 + c) * 2);
    f.u2[1] = *(const uint2*)((const char*)sh + (r * 72 + c + 16) * 2);
    return f.v;
}
// A-frag from f32 [64][68] LDS, scaled per-column, cvt to bf16
__device__ inline bf16x8 mfrag(const float* Msh, const float* colscale, int m0, int k0) {
    int lane = threadIdx.x & 63;
    int t = m0 + (lane & 15);
    int s0 = k0 + ((lane >> 4) * 4);
    U4S8 r;
#pragma unroll
    for (int i = 0; i < 4; ++i) {
        r.s[i]     = bfbits(Msh[t * 68 + s0 + i]      * colscale[s0 + i]);
        r.s[4 + i] = bfbits(Msh[t * 68 + s0 + 16 + i] * colscale[s0 + 16 + i]);
    }
    FragU f; f.u4 = r.u; return f.v;
}

// ---------------------------------------------------------------------------
// MFMA GEMM: C[m,n] = sum_k A[m,k]*B[n,k]; A: [M,K] (fp32 or bf16), B: [N,K]
// fp32. bf16 MFMA 16x16x32, fp32 accum. Tile 128x128xBK64, 4 waves.
// ---------------------------------------------------------------------------
template <typename TA, typename TC>
__global__ __launch_bounds__(256) void mfma_gemm_nt(const TA* __restrict__ A,
                                                    const float* __restrict__ B,
                                                    TC* __restrict__ C,
                                                    int M, int N, int K) {
    __shared__ __align__(16) short As[128 * 64];
    __shared__ __align__(16) short Bs[128 * 64];
    const int tid = threadIdx.x;
    const int lane = tid & 63;
    const int wid = tid >> 6;
    const int wr = wid >> 1, wc = wid & 1;
    const int bm = blockIdx.y * 128, bn = blockIdx.x * 128;
    const int srow = tid >> 1;
    const int sks = (tid & 1) * 32;

    f32x4 acc[4][4];
#pragma unroll
    for (int i = 0; i < 4; ++i)
#pragma unroll
        for (int j = 0; j < 4; ++j) acc[i][j] = f32x4{0.f, 0.f, 0.f, 0.f};

    auto swzb = [](int row, int kelem) {
        return ((row * 64 + kelem) * 2) ^ ((row & 7) << 4);
    };
    uint4 ra[4], rb[4];
    auto fetch = [&](int k0) {
        if constexpr (sizeof(TA) == 2) {
            const uint4* pa = (const uint4*)(A + (size_t)(bm + srow) * K + k0 + sks);
#pragma unroll
            for (int j = 0; j < 4; ++j) ra[j] = pa[j];
        } else {
            const float4* pa = (const float4*)(A + (size_t)(bm + srow) * K + k0 + sks);
#pragma unroll
            for (int j = 0; j < 4; ++j) ra[j] = pack8(pa[2 * j], pa[2 * j + 1]);
        }
        const float4* pb = (const float4*)(B + (size_t)(bn + srow) * K + k0 + sks);
#pragma unroll
        for (int j = 0; j < 4; ++j) rb[j] = pack8(pb[2 * j], pb[2 * j + 1]);
    };
    auto store_lds = [&]() {
#pragma unroll
        for (int j = 0; j < 4; ++j) {
            int byte = swzb(srow, sks + 8 * j);
            *(uint4*)((char*)As + byte) = ra[j];
            *(uint4*)((char*)Bs + byte) = rb[j];
        }
    };
    auto rdfrag = [&](const short* Sm, int row, int kbase) {
        FragU f;
        int ko = kbase + (lane >> 4) * 4;
        f.u2[0] = *(const uint2*)((const char*)Sm + swzb(row, ko));
        f.u2[1] = *(const uint2*)((const char*)Sm + swzb(row, ko + 16));
        return f.v;
    };

    fetch(0);
    for (int k0 = 0; k0 < K; k0 += 64) {
        __syncthreads();
        store_lds();
        __syncthreads();
        if (k0 + 64 < K) fetch(k0 + 64);
#pragma unroll
        for (int kk = 0; kk < 2; ++kk) {
            bf16x8 af[4], bfr[4];
#pragma unroll
            for (int i = 0; i < 4; ++i)
                af[i] = rdfrag(As, wr * 64 + i * 16 + (lane & 15), kk * 32);
#pragma unroll
            for (int j = 0; j < 4; ++j)
                bfr[j] = rdfrag(Bs, wc * 64 + j * 16 + (lane & 15), kk * 32);
#pragma unroll
            for (int i = 0; i < 4; ++i)
#pragma unroll
                for (int j = 0; j < 4; ++j)
                    acc[i][j] = __builtin_amdgcn_mfma_f32_16x16x32_bf16(
                        af[i], bfr[j], acc[i][j], 0, 0, 0);
        }
    }
#pragma unroll
    for (int i = 0; i < 4; ++i)
#pragma unroll
        for (int j = 0; j < 4; ++j) {
            int row = bm + wr * 64 + i * 16 + (lane >> 4) * 4;
            int col = bn + wc * 64 + j * 16 + (lane & 15);
#pragma unroll
            for (int qi = 0; qi < 4; ++qi) {
                float vv = acc[i][j][qi];
                if constexpr (sizeof(TC) == 2)
                    C[(size_t)(row + qi) * N + col] = __float2bfloat16(vv);
                else
                    C[(size_t)(row + qi) * N + col] = vv;
            }
        }
}

// ---------------------------------------------------------------------------
// causal depthwise conv4 + SiLU + per-head l2norm (+scale) for q/k.
// ---------------------------------------------------------------------------
__global__ __launch_bounds__(256) void convnorm_qk(const bf16* __restrict__ pre,
                                                   const float* __restrict__ cw,
                                                   bf16* __restrict__ out,
                                                   float scale) {
    const int bth = blockIdx.x;
    const int h = bth % NH;
    const int bt = bth / NH;
    const int t = bt % TT;
    const int d = threadIdx.x;
    const int c = h * DKk + d;
    const int C = NH * DKk;
    const bf16* p = pre + (size_t)bt * C + c;

    float w0 = cw[c * 4 + 0], w1 = cw[c * 4 + 1], w2 = cw[c * 4 + 2], w3 = cw[c * 4 + 3];
    float y = w3 * __bfloat162float(p[0]);
    if (t >= 1) y = fmaf(w2, __bfloat162float(p[-(ptrdiff_t)C]), y);
    if (t >= 2) y = fmaf(w1, __bfloat162float(p[-(ptrdiff_t)(2 * C)]), y);
    if (t >= 3) y = fmaf(w0, __bfloat162float(p[-(ptrdiff_t)(3 * C)]), y);
    y = y / (1.f + expf(-y));   // SiLU

    float s = y * y;
#pragma unroll
    for (int off = 32; off >= 1; off >>= 1) s += __shfl_down(s, off, 64);
    __shared__ float red[4];
    if ((threadIdx.x & 63) == 0) red[threadIdx.x >> 6] = s;
    __syncthreads();
    float tot = (red[0] + red[1]) + (red[2] + red[3]);
    out[(size_t)bt * C + c] = __float2bfloat16(y * rsqrtf(tot + 1e-6f) * scale);
}

// ---------------------------------------------------------------------------
// causal depthwise conv4 + SiLU for v.
// ---------------------------------------------------------------------------
__global__ __launch_bounds__(256) void conv_v_kernel(const bf16* __restrict__ pre,
                                                     const float* __restrict__ cw,
                                                     bf16* __restrict__ out) {
    const int C = NH * DVv;
    int idx = blockIdx.x * 256 + threadIdx.x;
    int c = idx % C;
    int bt = idx / C;
    int t = bt % TT;
    const bf16* p = pre + (size_t)bt * C + c;
    float y = cw[c * 4 + 3] * __bfloat162float(p[0]);
    if (t >= 1) y = fmaf(cw[c * 4 + 2], __bfloat162float(p[-(ptrdiff_t)C]), y);
    if (t >= 2) y = fmaf(cw[c * 4 + 1], __bfloat162float(p[-(ptrdiff_t)(2 * C)]), y);
    if (t >= 3) y = fmaf(cw[c * 4 + 0], __bfloat162float(p[-(ptrdiff_t)(3 * C)]), y);
    out[(size_t)bt * C + c] = __float2bfloat16(y / (1.f + expf(-y)));
}

// ---------------------------------------------------------------------------
// beta = sigmoid(x@Wb.T), g = -exp(A_log)*softplus(x@Wa.T + dt_bias)
// ---------------------------------------------------------------------------
__global__ __launch_bounds__(256) void proj_ab(const float* __restrict__ x,
                                               const float* __restrict__ Wb,
                                               const float* __restrict__ Wa,
                                               const float* __restrict__ A_log,
                                               const float* __restrict__ dt_bias,
                                               float* __restrict__ beta,
                                               float* __restrict__ g) {
    const int bt = blockIdx.x;
    const int tid = threadIdx.x;
    const float* xr = x + (size_t)bt * HIDDIM;
    float accb[NH], acca[NH];
#pragma unroll
    for (int h = 0; h < NH; ++h) { accb[h] = 0.f; acca[h] = 0.f; }
    for (int k0 = tid; k0 < HIDDIM; k0 += 256) {
        float xv = xr[k0];
#pragma unroll
        for (int h = 0; h < NH; ++h) {
            accb[h] = fmaf(xv, Wb[h * HIDDIM + k0], accb[h]);
            acca[h] = fmaf(xv, Wa[h * HIDDIM + k0], acca[h]);
        }
    }
#pragma unroll
    for (int h = 0; h < NH; ++h) {
#pragma unroll
        for (int off = 32; off >= 1; off >>= 1) {
            accb[h] += __shfl_down(accb[h], off, 64);
            acca[h] += __shfl_down(acca[h], off, 64);
        }
    }
    __shared__ float redb[NH][4], reda[NH][4];
    int wv = tid >> 6;
    if ((tid & 63) == 0) {
#pragma unroll
        for (int h = 0; h < NH; ++h) { redb[h][wv] = accb[h]; reda[h][wv] = acca[h]; }
    }
    __syncthreads();
    if (tid < NH) {
        float sb = (redb[tid][0] + redb[tid][1]) + (redb[tid][2] + redb[tid][3]);
        float sa = (reda[tid][0] + reda[tid][1]) + (reda[tid][2] + reda[tid][3]);
        beta[(size_t)bt * NH + tid] = 1.f / (1.f + expf(-sb));
        float xg = sa + dt_bias[tid];
        float sp = fmaxf(xg, 0.f) + log1pf(expf(-fabsf(xg)));
        g[(size_t)bt * NH + tid] = -expf(A_log[tid]) * sp;
    }
}

// ---------------------------------------------------------------------------
// CHUNK PREP (parallel over all 768 (b,h,chunk)):
//  L = cumsum(g); A = beta.e^{dL} o KK^T (strict lower); M = (I+A)^-1;
//  Tv = M(bV) -> wsB; Tk = M(b.Lam.K) -> v-slot cols [0,256);
//  K^T repack -> v-slot cols [256,512);
//  B = e^{dL} o QK^T (lower incl diag) -> Bmat; eC,LamC,lam -> scl.
//  NOTE: qbuf is READ-ONLY (lam folded into chunk_scan).
// ---------------------------------------------------------------------------
__global__ __launch_bounds__(256) void chunk_prep(const bf16* __restrict__ qbuf,
                                                  const bf16* __restrict__ kbuf,
                                                  bf16* __restrict__ vbuf,
                                                  bf16* __restrict__ tvbuf,
                                                  const float* __restrict__ gbuf,
                                                  const float* __restrict__ bbuf,
                                                  bf16* __restrict__ Bmat,
                                                  float* __restrict__ scl) {
    __shared__ __align__(16) short Ksh[64 * 256];
    __shared__ __align__(16) short Qsh[64 * 256];   // later: K_T [256][64]
    __shared__ __align__(16) float Ash[64 * 68];    // A, then M (in place)
    __shared__ __align__(16) short Vt[128 * 72];
    __shared__ float Lsh[64], betash[64], lamsh[64], blamsh[64];

    const int blk = blockIdx.x;
    const int c = blk % NCH;
    const int hh = (blk / NCH) % NH;
    const int b = blk / (NCH * NH);
    const int tid = threadIdx.x;
    const int wid = tid >> 6;
    const int lane = tid & 63;
    const int bt0 = b * TT + c * CH;
    const int cid = (b * NH + hh) * NCH + c;

    // stage K,Q (swizzled)
    {
        int r = tid >> 2, c0 = (tid & 3) * 64;
        const uint4* kg = (const uint4*)(kbuf + (size_t)(bt0 + r) * 1536 + hh * 256 + c0);
        const uint4* qg = (const uint4*)(qbuf + (size_t)(bt0 + r) * 1536 + hh * 256 + c0);
#pragma unroll
        for (int j = 0; j < 8; ++j) {
            int byte = ((r * 256 + c0 + j * 8) * 2) ^ ((r & 7) << 4);
            *(uint4*)((char*)Ksh + byte) = kg[j];
            *(uint4*)((char*)Qsh + byte) = qg[j];
        }
    }
    if (tid < 64) {
        float gv = gbuf[(size_t)(bt0 + tid) * NH + hh];
        float bv = bbuf[(size_t)(bt0 + tid) * NH + hh];
        float L = gv;
#pragma unroll
        for (int off = 1; off < 64; off <<= 1) {
            float o = __shfl_up(L, off, 64);
            if (lane >= off) L += o;
        }
        float L63 = __shfl(L, 63, 64);
        float lam = expf(L);
        Lsh[tid] = L; betash[tid] = bv; lamsh[tid] = lam; blamsh[tid] = bv * lam;
        scl[(size_t)cid * SCLN + tid] = expf(L63 - L);
        scl[(size_t)cid * SCLN + 68 + tid] = lam;
        if (tid == 63) scl[(size_t)cid * SCLN + 64] = lam;  // LamC = e^{L63}
    }
    __syncthreads();

    // KK^T and QK^T
    f32x4 akk[4], aqk[4];
#pragma unroll
    for (int n = 0; n < 4; ++n) { akk[n] = f32x4{0,0,0,0}; aqk[n] = f32x4{0,0,0,0}; }
#pragma unroll
    for (int kk = 0; kk < 8; ++kk) {
        bf16x8 aK = lfrag256(Ksh, wid * 16, kk * 32);
        bf16x8 aQ = lfrag256(Qsh, wid * 16, kk * 32);
#pragma unroll
        for (int n = 0; n < 4; ++n) {
            bf16x8 bK = lfrag256(Ksh, n * 16, kk * 32);
            akk[n] = __builtin_amdgcn_mfma_f32_16x16x32_bf16(aK, bK, akk[n], 0, 0, 0);
            aqk[n] = __builtin_amdgcn_mfma_f32_16x16x32_bf16(aQ, bK, aqk[n], 0, 0, 0);
        }
    }
    // A_mat + B_mat (C layout: row=(lane>>4)*4+qi, col=lane&15)
#pragma unroll
    for (int n = 0; n < 4; ++n)
#pragma unroll
        for (int qi = 0; qi < 4; ++qi) {
            int i = wid * 16 + (lane >> 4) * 4 + qi;
            int s = n * 16 + (lane & 15);
            float av = 0.f, bvv = 0.f;
            if (s <= i) {
                float sc2 = expf(Lsh[i] - Lsh[s]);
                if (s < i) av = betash[i] * sc2 * akk[n][qi];
                bvv = sc2 * aqk[n][qi];
            }
            Ash[i * 68 + s] = av;
            Bmat[(size_t)cid * 4096 + i * 64 + s] = __float2bfloat16(bvv);
        }
    __syncthreads();

    // solve M = (I+A)^-1 (wave 0, lane = column)
    if (wid == 0) {
        float mm[64];
        mm[0] = (lane == 0) ? 1.f : 0.f;
#pragma unroll
        for (int t = 1; t < 64; ++t) {
            float a0 = 0.f, a1 = 0.f, a2 = 0.f, a3 = 0.f;
#pragma unroll
            for (int s = 0; s < t; ++s) {
                float Av = Ash[t * 68 + s];
                if ((s & 3) == 0) a0 = fmaf(Av, mm[s], a0);
                else if ((s & 3) == 1) a1 = fmaf(Av, mm[s], a1);
                else if ((s & 3) == 2) a2 = fmaf(Av, mm[s], a2);
                else a3 = fmaf(Av, mm[s], a3);
            }
            mm[t] = ((t == lane) ? 1.f : 0.f) - ((a0 + a1) + (a2 + a3));
        }
#pragma unroll
        for (int t = 0; t < 64; ++t) Ash[t * 68 + lane] = mm[t];
    }
    __syncthreads();

    // Tv = M(bV) in 4 d-quarters of 128
    for (int q = 0; q < 4; ++q) {
        {   // stage V quarter transposed: Vt[d][i]
            int i = tid >> 2, d0 = (tid & 3) * 32;
            const uint4* vg = (const uint4*)(vbuf + (size_t)(bt0 + i) * 3072 + hh * 512 + q * 128 + d0);
#pragma unroll
            for (int jb = 0; jb < 4; ++jb) {
                U4S8 u; u.u = vg[jb];
#pragma unroll
                for (int e = 0; e < 8; ++e)
                    Vt[(d0 + jb * 8 + e) * 72 + i] = (short)u.s[e];
            }
        }
        __syncthreads();
        f32x4 acc[8];
#pragma unroll
        for (int n = 0; n < 8; ++n) acc[n] = f32x4{0,0,0,0};
#pragma unroll
        for (int kk = 0; kk < 2; ++kk) {
            bf16x8 am = mfrag(Ash, betash, wid * 16, kk * 32);
#pragma unroll
            for (int n = 0; n < 8; ++n) {
                bf16x8 bv8 = lfrag72(Vt, n * 16, kk * 32);
                acc[n] = __builtin_amdgcn_mfma_f32_16x16x32_bf16(am, bv8, acc[n], 0, 0, 0);
            }
        }
#pragma unroll
        for (int n = 0; n < 8; ++n)
#pragma unroll
            for (int qi = 0; qi < 4; ++qi) {
                int t = wid * 16 + (lane >> 4) * 4 + qi;
                int d = q * 128 + n * 16 + (lane & 15);
                tvbuf[(size_t)(bt0 + t) * 3072 + hh * 512 + d] = __float2bfloat16(acc[n][qi]);
            }
        __syncthreads();
    }

    // build K_T [256][64] into Qsh (swizzled)
    {
        int j = tid;
        unsigned short rowv[64];
#pragma unroll
        for (int s = 0; s < 64; ++s)
            rowv[s] = *(const unsigned short*)((const char*)Ksh + (((s * 256 + j) * 2) ^ ((s & 7) << 4)));
#pragma unroll
        for (int sb = 0; sb < 8; ++sb) {
            U4S8 u;
#pragma unroll
            for (int e = 0; e < 8; ++e) u.s[e] = rowv[sb * 8 + e];
            *(uint4*)((char*)Qsh + (((j * 64 + sb * 8) * 2) ^ ((j & 7) << 4))) = u.u;
        }
    }
    __syncthreads();

    // Tk = M(b.Lam.K): A = M*blam, B = K_T
    {
        f32x4 acc[16];
#pragma unroll
        for (int n = 0; n < 16; ++n) acc[n] = f32x4{0,0,0,0};
#pragma unroll
        for (int kk = 0; kk < 2; ++kk) {
            bf16x8 am = mfrag(Ash, blamsh, wid * 16, kk * 32);
#pragma unroll
            for (int n = 0; n < 16; ++n) {
                bf16x8 bk = lfrag64(Qsh, n * 16, kk * 32);
                acc[n] = __builtin_amdgcn_mfma_f32_16x16x32_bf16(am, bk, acc[n], 0, 0, 0);
            }
        }
#pragma unroll
        for (int n = 0; n < 16; ++n)
#pragma unroll
            for (int qi = 0; qi < 4; ++qi) {
                int t = wid * 16 + (lane >> 4) * 4 + qi;
                int j = n * 16 + (lane & 15);
                vbuf[(size_t)(bt0 + t) * 3072 + hh * 512 + j] = __float2bfloat16(acc[n][qi]);
            }
    }
    // flush K_T -> global segment layout: row i=j>>2 of chunk, cols 256 + (j&3)*64 + s
    {
        int j = tid;
#pragma unroll
        for (int sb = 0; sb < 8; ++sb) {
            uint4 u = *(uint4*)((char*)Qsh + (((j * 64 + sb * 8) * 2) ^ ((j & 7) << 4)));
            *(uint4*)(vbuf + (size_t)(bt0 + (j >> 2)) * 3072 + hh * 512 + 256 + (j & 3) * 64 + sb * 8) = u;
        }
    }
}

// ---------------------------------------------------------------------------
// CHUNK SCAN (sequential over 64 chunks; 48 blocks = 12 bh x 4 DV-slices).
// Per wave: 32 DV cols; S kept as MFMA accs (f32) + per-wave LDS bf16 mirror.
// No __syncthreads (all LDS is wave-private). Per chunk:
//   U = Tv - Tk.S ; O = lam_t*(Q.S) + B.U -> over Tv slice (in place);
//   S = LamC.S + K^T (eC o U)
// ---------------------------------------------------------------------------
__global__ __launch_bounds__(256, 1) void chunk_scan(const bf16* __restrict__ qbuf,
                                                     const bf16* __restrict__ vbuf,
                                                     bf16* __restrict__ tvbuf,
                                                     const bf16* __restrict__ Bmat,
                                                     const float* __restrict__ scl) {
    __shared__ __align__(16) short Ssh[4][32 * 256];
    __shared__ __align__(16) short Ush[4][32 * 72];
    __shared__ __align__(16) short Utsh[4][32 * 72];
    const int tid = threadIdx.x;
    const int wid = tid >> 6;
    const int lane = tid & 63;
    const int q4 = blockIdx.x & 3;
    const int bh = blockIdx.x >> 2;
    const int hh = bh % NH;
    const int b = bh / NH;
    const int dglob0 = hh * 512 + q4 * 128 + wid * 32;  // this wave's first DV col

    short* S = Ssh[wid];
    short* Uw = Ush[wid];
    short* Utw = Utsh[wid];

    {   // zero S slice (16KB per wave)
        uint4 z{0, 0, 0, 0};
#pragma unroll
        for (int j = 0; j < 16; ++j) *(uint4*)((char*)S + lane * 256 + j * 16) = z;
    }
    f32x4 accS[2][16];
#pragma unroll
    for (int m = 0; m < 2; ++m)
#pragma unroll
        for (int n = 0; n < 16; ++n) accS[m][n] = f32x4{0, 0, 0, 0};

    for (int c = 0; c < NCH; ++c) {
        const int bt0 = b * TT + c * CH;
        const int cid = (b * NH + hh) * NCH + c;
        const float lamC = scl[(size_t)cid * SCLN + 64];

        // A-frags of S (bf16 mirror)
        bf16x8 aS[2][8];
#pragma unroll
        for (int m = 0; m < 2; ++m)
#pragma unroll
            for (int kk = 0; kk < 8; ++kk) aS[m][kk] = lfrag256(S, m * 16, kk * 32);

        // P = Tk.S-slice, QS = Q.S
        f32x4 accP[2][4], accQ[2][4];
#pragma unroll
        for (int m = 0; m < 2; ++m)
#pragma unroll
            for (int n = 0; n < 4; ++n) { accP[m][n] = f32x4{0,0,0,0}; accQ[m][n] = f32x4{0,0,0,0}; }
#pragma unroll
        for (int nf = 0; nf < 4; ++nf) {
#pragma unroll
            for (int kk = 0; kk < 8; ++kk) {
                bf16x8 bT = gfrag(vbuf + (size_t)bt0 * 3072 + hh * 512, 3072, nf * 16, kk * 32);
                bf16x8 bQ = gfrag(qbuf + (size_t)bt0 * 1536 + hh * 256, 1536, nf * 16, kk * 32);
#pragma unroll
                for (int m = 0; m < 2; ++m) {
                    accP[m][nf] = __builtin_amdgcn_mfma_f32_16x16x32_bf16(aS[m][kk], bT, accP[m][nf], 0, 0, 0);
                    accQ[m][nf] = __builtin_amdgcn_mfma_f32_16x16x32_bf16(aS[m][kk], bQ, accQ[m][nf], 0, 0, 0);
                }
            }
        }
        // scale QS by lam_t (lam folded here instead of mutating qbuf)
#pragma unroll
        for (int nf = 0; nf < 4; ++nf) {
            float lamt = scl[(size_t)cid * SCLN + 68 + nf * 16 + (lane & 15)];
#pragma unroll
            for (int m = 0; m < 2; ++m)
#pragma unroll
                for (int qi = 0; qi < 4; ++qi) accQ[m][nf][qi] *= lamt;
        }
        // U = Tv - P; write U and eC*U tiles
#pragma unroll
        for (int nf = 0; nf < 4; ++nf) {
            int t = nf * 16 + (lane & 15);
            float eCt = scl[(size_t)cid * SCLN + t];
#pragma unroll
            for (int m = 0; m < 2; ++m) {
                int d0 = m * 16 + (lane >> 4) * 4;
                const bf16* tvp = tvbuf + (size_t)(bt0 + t) * 3072 + dglob0 + d0;
                uint2 u2 = *(const uint2*)tvp;
                float tvv[4] = { bflo(u2.x), bfhi(u2.x), bflo(u2.y), bfhi(u2.y) };
#pragma unroll
                for (int qi = 0; qi < 4; ++qi) {
                    float uu = tvv[qi] - accP[m][nf][qi];
                    Uw[(d0 + qi) * 72 + t] = bfbits(uu);
                    Utw[(d0 + qi) * 72 + t] = bfbits(uu * eCt);
                }
            }
        }
        // O = lam*QS + B.U (accumulate into accQ)
        bf16x8 aU[2][2];
#pragma unroll
        for (int m = 0; m < 2; ++m)
#pragma unroll
            for (int k2 = 0; k2 < 2; ++k2) aU[m][k2] = lfrag72(Uw, m * 16, k2 * 32);
#pragma unroll
        for (int nf = 0; nf < 4; ++nf)
#pragma unroll
            for (int k2 = 0; k2 < 2; ++k2) {
                bf16x8 bB = gfrag(Bmat + (size_t)cid * 4096, 64, nf * 16, k2 * 32);
#pragma unroll
                for (int m = 0; m < 2; ++m)
                    accQ[m][nf] = __builtin_amdgcn_mfma_f32_16x16x32_bf16(aU[m][k2], bB, accQ[m][nf], 0, 0, 0);
            }
        // store O over the Tv slice (read-before-write within this wave done)
#pragma unroll
        for (int nf = 0; nf < 4; ++nf)
#pragma unroll
            for (int m = 0; m < 2; ++m) {
                int t = nf * 16 + (lane & 15);
                int d0 = m * 16 + (lane >> 4) * 4;
                bf16* op = tvbuf + (size_t)(bt0 + t) * 3072 + dglob0 + d0;
                *(uint2*)op = packh4(accQ[m][nf][0], accQ[m][nf][1], accQ[m][nf][2], accQ[m][nf][3]);
            }
        // S = LamC*S + K^T(eC o U)
#pragma unroll
        for (int m = 0; m < 2; ++m)
#pragma unroll
            for (int n = 0; n < 16; ++n) accS[m][n] *= lamC;
        bf16x8 aUt[2][2];
#pragma unroll
        for (int m = 0; m < 2; ++m)
#pragma unroll
            for (int k2 = 0; k2 < 2; ++k2) aUt[m][k2] = lfrag72(Utw, m * 16, k2 * 32);
#pragma unroll
        for (int nf = 0; nf < 16; ++nf)
#pragma unroll
            for (int k2 = 0; k2 < 2; ++k2) {
                int j = nf * 16 + (lane & 15);
                const bf16* kp = vbuf + (size_t)(bt0 + (j >> 2)) * 3072 + hh * 512 + 256 +
                                 (j & 3) * 64 + k2 * 32 + ((lane >> 4) * 4);
                FragU f;
                f.u2[0] = *(const uint2*)kp;
                f.u2[1] = *(const uint2*)(kp + 16);
#pragma unroll
                for (int m = 0; m < 2; ++m)
                    accS[m][nf] = __builtin_amdgcn_mfma_f32_16x16x32_bf16(aUt[m][k2], f.v, accS[m][nf], 0, 0, 0);
            }
        // refresh bf16 mirror of S
#pragma unroll
        for (int m = 0; m < 2; ++m)
#pragma unroll
            for (int nf = 0; nf < 16; ++nf)
#pragma unroll
                for (int qi = 0; qi < 4; ++qi) {
                    int d = m * 16 + (lane >> 4) * 4 + qi;
                    int j = nf * 16 + (lane & 15);
                    *(short*)((char*)S + (((d * 256 + j) * 2) ^ ((d & 7) << 4))) =
                        (short)bfbits(accS[m][nf][qi]);
                }
    }
}

// ---------------------------------------------------------------------------
// per-head RMSNorm (eps 1e-5) * norm_w, then * silu(gate). In-place (bf16).
// ---------------------------------------------------------------------------
__global__ __launch_bounds__(256) void rmsgate_kernel(bf16* __restrict__ o,
                                                      const bf16* __restrict__ gate,
                                                      const float* __restrict__ norm_w) {
    const int bhead = blockIdx.x;
    const int d = threadIdx.x;
    bf16* op = o + (size_t)bhead * DVv;
    const bf16* gp = gate + (size_t)bhead * DVv;
    float x0 = __bfloat162float(op[d]), x1 = __bfloat162float(op[d + 256]);
    float s = x0 * x0 + x1 * x1;
#pragma unroll
    for (int off = 32; off >= 1; off >>= 1) s += __shfl_down(s, off, 64);
    __shared__ float red[4];
    if ((threadIdx.x & 63) == 0) red[threadIdx.x >> 6] = s;
    __syncthreads();
    float tot = (red[0] + red[1]) + (red[2] + red[3]);
    float r = rsqrtf(tot * (1.f / DVv) + 1e-5f);
    float g0 = __bfloat162float(gp[d]), g1 = __bfloat162float(gp[d + 256]);
    g0 = g0 / (1.f + expf(-g0));
    g1 = g1 / (1.f + expf(-g1));
    op[d]       = __float2bfloat16(x0 * r * norm_w[d] * g0);
    op[d + 256] = __float2bfloat16(x1 * r * norm_w[d + 256] * g1);
}

__global__ void fill_kernel(float* p, int n, float v) {
    int i = blockIdx.x * 256 + threadIdx.x;
    if (i < n) p[i] = v;
}

// ---------------------------------------------------------------------------
extern "C" void kernel_launch(void* const* d_in, const int* in_sizes, int n_in,
                              void* d_out, int out_size, void* d_ws, size_t ws_size,
                              hipStream_t stream) {
    const float* x       = (const float*)d_in[0];
    const float* Wq      = (const float*)d_in[1];
    const float* Wk      = (const float*)d_in[2];
    const float* Wv      = (const float*)d_in[3];
    const float* Wb      = (const float*)d_in[4];
    const float* Wa      = (const float*)d_in[5];
    const float* A_log   = (const float*)d_in[6];
    const float* dt_bias = (const float*)d_in[7];
    const float* cwq     = (const float*)d_in[8];
    const float* cwk     = (const float*)d_in[9];
    const float* cwv     = (const float*)d_in[10];
    const float* Wg      = (const float*)d_in[11];
    const float* norm_w  = (const float*)d_in[12];
    const float* Wo      = (const float*)d_in[13];
    float* out = (float*)d_out;

    // d_out scratch: qb/kb ONLY (write-once-read-later pattern, replay-proven
    // in rounds 2-5). Both dead before the final GEMM overwrites d_out.
    bf16* qb = (bf16*)d_out;                          // [8192,1536]
    bf16* kb = qb + (size_t)MTOK * 1536;              // [8192,1536]

    // ws: A = {preQ|preK | v -> Tk/K_T | gate}, B = {preV | Tv -> O},
    //     Bmat, scl, beta, g.
    const size_t elemsA = (size_t)MTOK * 3072;
    const size_t elemsB = (size_t)MTOK * 3072;
    bf16* wsA   = (bf16*)d_ws;
    bf16* wsB   = wsA + elemsA;
    bf16* Bmat  = wsB + elemsB;                       // [768][64][64]
    float* scl  = (float*)(Bmat + (size_t)NBb * NH * NCH * 4096);  // [768][136]
    float* betab = scl + (size_t)NBb * NH * NCH * SCLN;
    float* gb    = betab + (size_t)MTOK * NH;
    size_t need = ((size_t)(gb - (float*)d_ws) + (size_t)MTOK * NH) * sizeof(float);
    if (ws_size < need) {
        fill_kernel<<<(out_size + 255) / 256, 256, 0, stream>>>(out, out_size, 1e9f);
        return;
    }

    dim3 blk(256);
    // q projection -> conv+silu+l2norm (*DK^-0.5)
    mfma_gemm_nt<float, bf16><<<dim3(12, 64), blk, 0, stream>>>(x, Wq, wsA, MTOK, 1536, HIDDIM);
    convnorm_qk<<<MTOK * NH, dim3(DKk), 0, stream>>>(wsA, cwq, qb, 0.0625f);
    // k projection -> conv+silu+l2norm
    mfma_gemm_nt<float, bf16><<<dim3(12, 64), blk, 0, stream>>>(x, Wk, wsA, MTOK, 1536, HIDDIM);
    convnorm_qk<<<MTOK * NH, dim3(DKk), 0, stream>>>(wsA, cwk, kb, 1.0f);
    // v projection (into B) -> conv+silu (into A)
    mfma_gemm_nt<float, bf16><<<dim3(24, 64), blk, 0, stream>>>(x, Wv, wsB, MTOK, 3072, HIDDIM);
    conv_v_kernel<<<(MTOK * 3072) / 256, blk, 0, stream>>>(wsB, cwv, wsA);
    // beta / g
    proj_ab<<<MTOK, blk, 0, stream>>>(x, Wb, Wa, A_log, dt_bias, betab, gb);
    // chunked delta rule: prep (parallel) + scan (sequential over chunks)
    chunk_prep<<<NBb * NH * NCH, blk, 0, stream>>>(qb, kb, wsA, wsB, gb, betab, Bmat, scl);
    chunk_scan<<<NBb * NH * 4, blk, 0, stream>>>(qb, wsA, wsB, Bmat, scl);
    // gate projection into A (Tk/K_T dead after scan)
    mfma_gemm_nt<float, bf16><<<dim3(24, 64), blk, 0, stream>>>(x, Wg, wsA, MTOK, 3072, HIDDIM);
    // rmsnorm + silu(gate), in place on O (wsB)
    rmsgate_kernel<<<MTOK * NH, blk, 0, stream>>>(wsB, wsA, norm_w);
    // output projection: O (bf16, wsB) x Wo (fp32) -> d_out fp32
    mfma_gemm_nt<bf16, float><<<dim3(16, 64), blk, 0, stream>>>(wsB, Wo, out, MTOK, 2048, 3072);
}

// Round 8
// 3519.794 us; speedup vs baseline: 24.3481x; 1.1352x over previous
//
#include <hip/hip_runtime.h>
#include <hip/hip_bf16.h>
#include <math.h>

#define NH 6
#define DKk 256
#define DVv 512
#define HIDDIM 2048
#define TT 4096
#define NBb 2
#define MTOK (NBb*TT)   // 8192
#define CH 64
#define NCH (TT/CH)     // 64 chunks per sequence
#define SCLN 136

typedef __hip_bfloat16 bf16;
typedef __attribute__((ext_vector_type(8))) short bf16x8;
typedef __attribute__((ext_vector_type(4))) float f32x4;

union FragU { bf16x8 v; uint2 u2[2]; uint4 u4; };
union BfBits { bf16 h; unsigned short s; };
union U4S8 { uint4 u; unsigned short s[8]; };

__device__ inline float bflo(unsigned u) { return __uint_as_float(u << 16); }
__device__ inline float bfhi(unsigned u) { return __uint_as_float(u & 0xffff0000u); }
__device__ inline unsigned short bfbits(float f) {
    BfBits b; b.h = __float2bfloat16(f); return b.s;
}
__device__ inline float bf2f(unsigned short s) { return __uint_as_float(((unsigned)s) << 16); }
__device__ inline uint4 pack8(float4 a, float4 b) {
    U4S8 r;
    r.s[0] = bfbits(a.x); r.s[1] = bfbits(a.y); r.s[2] = bfbits(a.z); r.s[3] = bfbits(a.w);
    r.s[4] = bfbits(b.x); r.s[5] = bfbits(b.y); r.s[6] = bfbits(b.z); r.s[7] = bfbits(b.w);
    return r.u;
}
__device__ inline uint2 packh4(float a, float b, float c, float d) {
    union { unsigned short s[4]; uint2 u; } r;
    r.s[0] = bfbits(a); r.s[1] = bfbits(b); r.s[2] = bfbits(c); r.s[3] = bfbits(d);
    return r.u;
}
// pack two f32x4 C-tiles (same lane) into a bf16x8 B-frag (C-tile->B-frag identity)
__device__ inline bf16x8 pk8t(f32x4 a, f32x4 b) {
    U4S8 r;
    r.s[0] = bfbits(a[0]); r.s[1] = bfbits(a[1]); r.s[2] = bfbits(a[2]); r.s[3] = bfbits(a[3]);
    r.s[4] = bfbits(b[0]); r.s[5] = bfbits(b[1]); r.s[6] = bfbits(b[2]); r.s[7] = bfbits(b[3]);
    FragU f; f.u4 = r.u; return f.v;
}

// A/B-fragment loader from global. lane: row = n0+(lane&15),
// k = k0+(lane>>4)*4+{0..3} and +16+{0..3} (consistent across all operands).
__device__ inline bf16x8 gfrag(const bf16* base, size_t stride, int n0, int k0) {
    int lane = threadIdx.x & 63;
    const bf16* p = base + (size_t)(n0 + (lane & 15)) * stride + k0 + ((lane >> 4) * 4);
    FragU f; f.u2[0] = *(const uint2*)p; f.u2[1] = *(const uint2*)(p + 16);
    return f.v;
}
// LDS tile stride 256 elems, XOR-swizzled by ((row&7)<<4) on byte offset
__device__ inline bf16x8 lfrag256(const short* sh, int n0, int k0) {
    int lane = threadIdx.x & 63;
    int r = n0 + (lane & 15);
    int c = k0 + ((lane >> 4) * 4);
    FragU f;
    f.u2[0] = *(const uint2*)((const char*)sh + (((r * 256 + c) * 2) ^ ((r & 7) << 4)));
    f.u2[1] = *(const uint2*)((const char*)sh + (((r * 256 + c + 16) * 2) ^ ((r & 7) << 4)));
    return f.v;
}
// LDS tile stride 64 elems, swizzled
__device__ inline bf16x8 lfrag64(const short* sh, int n0, int k0) {
    int lane = threadIdx.x & 63;
    int r = n0 + (lane & 15);
    int c = k0 + ((lane >> 4) * 4);
    FragU f;
    f.u2[0] = *(const uint2*)((const char*)sh + (((r * 64 + c) * 2) ^ ((r & 7) << 4)));
    f.u2[1] = *(const uint2*)((const char*)sh + (((r * 64 + c + 16) * 2) ^ ((r & 7) << 4)));
    return f.v;
}
// LDS tile stride 72 elems (padded), no swizzle
__device__ inline bf16x8 lfrag72(const short* sh, int n0, int k0) {
    int lane = threadIdx.x & 63;
    int r = n0 + (lane & 15);
    int c = k0 + ((lane >> 4) * 4);
    FragU f;
    f.u2[0] = *(const uint2*)((const char*)sh + (r * 72 + c) * 2);
    f.u2[1] = *(const uint2*)((const char*)sh + (r * 72 + c + 16) * 2);
    return f.v;
}
// A-frag from f32 [64][68] LDS, scaled per-column, cvt to bf16
__device__ inline bf16x8 mfrag(const float* Msh, const float* colscale, int m0, int k0) {
    int lane = threadIdx.x & 63;
    int t = m0 + (lane & 15);
    int s0 = k0 + ((lane >> 4) * 4);
    U4S8 r;
#pragma unroll
    for (int i = 0; i < 4; ++i) {
        r.s[i]     = bfbits(Msh[t * 68 + s0 + i]      * colscale[s0 + i]);
        r.s[4 + i] = bfbits(Msh[t * 68 + s0 + 16 + i] * colscale[s0 + 16 + i]);
    }
    FragU f; f.u4 = r.u; return f.v;
}

// ---------------------------------------------------------------------------
// MFMA GEMM: C[m,n] = sum_k A[m,k]*B[n,k]; A: [M,K] (fp32 or bf16), B: [N,K]
// fp32. bf16 MFMA 16x16x32, fp32 accum. Tile 128x128xBK64, 4 waves.
// ---------------------------------------------------------------------------
template <typename TA, typename TC>
__global__ __launch_bounds__(256) void mfma_gemm_nt(const TA* __restrict__ A,
                                                    const float* __restrict__ B,
                                                    TC* __restrict__ C,
                                                    int M, int N, int K) {
    __shared__ __align__(16) short As[128 * 64];
    __shared__ __align__(16) short Bs[128 * 64];
    const int tid = threadIdx.x;
    const int lane = tid & 63;
    const int wid = tid >> 6;
    const int wr = wid >> 1, wc = wid & 1;
    const int bm = blockIdx.y * 128, bn = blockIdx.x * 128;
    const int srow = tid >> 1;
    const int sks = (tid & 1) * 32;

    f32x4 acc[4][4];
#pragma unroll
    for (int i = 0; i < 4; ++i)
#pragma unroll
        for (int j = 0; j < 4; ++j) acc[i][j] = f32x4{0.f, 0.f, 0.f, 0.f};

    auto swzb = [](int row, int kelem) {
        return ((row * 64 + kelem) * 2) ^ ((row & 7) << 4);
    };
    uint4 ra[4], rb[4];
    auto fetch = [&](int k0) {
        if constexpr (sizeof(TA) == 2) {
            const uint4* pa = (const uint4*)(A + (size_t)(bm + srow) * K + k0 + sks);
#pragma unroll
            for (int j = 0; j < 4; ++j) ra[j] = pa[j];
        } else {
            const float4* pa = (const float4*)(A + (size_t)(bm + srow) * K + k0 + sks);
#pragma unroll
            for (int j = 0; j < 4; ++j) ra[j] = pack8(pa[2 * j], pa[2 * j + 1]);
        }
        const float4* pb = (const float4*)(B + (size_t)(bn + srow) * K + k0 + sks);
#pragma unroll
        for (int j = 0; j < 4; ++j) rb[j] = pack8(pb[2 * j], pb[2 * j + 1]);
    };
    auto store_lds = [&]() {
#pragma unroll
        for (int j = 0; j < 4; ++j) {
            int byte = swzb(srow, sks + 8 * j);
            *(uint4*)((char*)As + byte) = ra[j];
            *(uint4*)((char*)Bs + byte) = rb[j];
        }
    };
    auto rdfrag = [&](const short* Sm, int row, int kbase) {
        FragU f;
        int ko = kbase + (lane >> 4) * 4;
        f.u2[0] = *(const uint2*)((const char*)Sm + swzb(row, ko));
        f.u2[1] = *(const uint2*)((const char*)Sm + swzb(row, ko + 16));
        return f.v;
    };

    fetch(0);
    for (int k0 = 0; k0 < K; k0 += 64) {
        __syncthreads();
        store_lds();
        __syncthreads();
        if (k0 + 64 < K) fetch(k0 + 64);
#pragma unroll
        for (int kk = 0; kk < 2; ++kk) {
            bf16x8 af[4], bfr[4];
#pragma unroll
            for (int i = 0; i < 4; ++i)
                af[i] = rdfrag(As, wr * 64 + i * 16 + (lane & 15), kk * 32);
#pragma unroll
            for (int j = 0; j < 4; ++j)
                bfr[j] = rdfrag(Bs, wc * 64 + j * 16 + (lane & 15), kk * 32);
#pragma unroll
            for (int i = 0; i < 4; ++i)
#pragma unroll
                for (int j = 0; j < 4; ++j)
                    acc[i][j] = __builtin_amdgcn_mfma_f32_16x16x32_bf16(
                        af[i], bfr[j], acc[i][j], 0, 0, 0);
        }
    }
#pragma unroll
    for (int i = 0; i < 4; ++i)
#pragma unroll
        for (int j = 0; j < 4; ++j) {
            int row = bm + wr * 64 + i * 16 + (lane >> 4) * 4;
            int col = bn + wc * 64 + j * 16 + (lane & 15);
#pragma unroll
            for (int qi = 0; qi < 4; ++qi) {
                float vv = acc[i][j][qi];
                if constexpr (sizeof(TC) == 2)
                    C[(size_t)(row + qi) * N + col] = __float2bfloat16(vv);
                else
                    C[(size_t)(row + qi) * N + col] = vv;
            }
        }
}

// ---------------------------------------------------------------------------
// causal depthwise conv4 + SiLU + per-head l2norm (+scale) for q/k.
// ---------------------------------------------------------------------------
__global__ __launch_bounds__(256) void convnorm_qk(const bf16* __restrict__ pre,
                                                   const float* __restrict__ cw,
                                                   bf16* __restrict__ out,
                                                   float scale) {
    const int bth = blockIdx.x;
    const int h = bth % NH;
    const int bt = bth / NH;
    const int t = bt % TT;
    const int d = threadIdx.x;
    const int c = h * DKk + d;
    const int C = NH * DKk;
    const bf16* p = pre + (size_t)bt * C + c;

    float w0 = cw[c * 4 + 0], w1 = cw[c * 4 + 1], w2 = cw[c * 4 + 2], w3 = cw[c * 4 + 3];
    float y = w3 * __bfloat162float(p[0]);
    if (t >= 1) y = fmaf(w2, __bfloat162float(p[-(ptrdiff_t)C]), y);
    if (t >= 2) y = fmaf(w1, __bfloat162float(p[-(ptrdiff_t)(2 * C)]), y);
    if (t >= 3) y = fmaf(w0, __bfloat162float(p[-(ptrdiff_t)(3 * C)]), y);
    y = y / (1.f + expf(-y));   // SiLU

    float s = y * y;
#pragma unroll
    for (int off = 32; off >= 1; off >>= 1) s += __shfl_down(s, off, 64);
    __shared__ float red[4];
    if ((threadIdx.x & 63) == 0) red[threadIdx.x >> 6] = s;
    __syncthreads();
    float tot = (red[0] + red[1]) + (red[2] + red[3]);
    out[(size_t)bt * C + c] = __float2bfloat16(y * rsqrtf(tot + 1e-6f) * scale);
}

// ---------------------------------------------------------------------------
// causal depthwise conv4 + SiLU for v.
// ---------------------------------------------------------------------------
__global__ __launch_bounds__(256) void conv_v_kernel(const bf16* __restrict__ pre,
                                                     const float* __restrict__ cw,
                                                     bf16* __restrict__ out) {
    const int C = NH * DVv;
    int idx = blockIdx.x * 256 + threadIdx.x;
    int c = idx % C;
    int bt = idx / C;
    int t = bt % TT;
    const bf16* p = pre + (size_t)bt * C + c;
    float y = cw[c * 4 + 3] * __bfloat162float(p[0]);
    if (t >= 1) y = fmaf(cw[c * 4 + 2], __bfloat162float(p[-(ptrdiff_t)C]), y);
    if (t >= 2) y = fmaf(cw[c * 4 + 1], __bfloat162float(p[-(ptrdiff_t)(2 * C)]), y);
    if (t >= 3) y = fmaf(cw[c * 4 + 0], __bfloat162float(p[-(ptrdiff_t)(3 * C)]), y);
    out[(size_t)bt * C + c] = __float2bfloat16(y / (1.f + expf(-y)));
}

// ---------------------------------------------------------------------------
// beta = sigmoid(x@Wb.T), g = -exp(A_log)*softplus(x@Wa.T + dt_bias)
// ---------------------------------------------------------------------------
__global__ __launch_bounds__(256) void proj_ab(const float* __restrict__ x,
                                               const float* __restrict__ Wb,
                                               const float* __restrict__ Wa,
                                               const float* __restrict__ A_log,
                                               const float* __restrict__ dt_bias,
                                               float* __restrict__ beta,
                                               float* __restrict__ g) {
    const int bt = blockIdx.x;
    const int tid = threadIdx.x;
    const float* xr = x + (size_t)bt * HIDDIM;
    float accb[NH], acca[NH];
#pragma unroll
    for (int h = 0; h < NH; ++h) { accb[h] = 0.f; acca[h] = 0.f; }
    for (int k0 = tid; k0 < HIDDIM; k0 += 256) {
        float xv = xr[k0];
#pragma unroll
        for (int h = 0; h < NH; ++h) {
            accb[h] = fmaf(xv, Wb[h * HIDDIM + k0], accb[h]);
            acca[h] = fmaf(xv, Wa[h * HIDDIM + k0], acca[h]);
        }
    }
#pragma unroll
    for (int h = 0; h < NH; ++h) {
#pragma unroll
        for (int off = 32; off >= 1; off >>= 1) {
            accb[h] += __shfl_down(accb[h], off, 64);
            acca[h] += __shfl_down(acca[h], off, 64);
        }
    }
    __shared__ float redb[NH][4], reda[NH][4];
    int wv = tid >> 6;
    if ((tid & 63) == 0) {
#pragma unroll
        for (int h = 0; h < NH; ++h) { redb[h][wv] = accb[h]; reda[h][wv] = acca[h]; }
    }
    __syncthreads();
    if (tid < NH) {
        float sb = (redb[tid][0] + redb[tid][1]) + (redb[tid][2] + redb[tid][3]);
        float sa = (reda[tid][0] + reda[tid][1]) + (reda[tid][2] + reda[tid][3]);
        beta[(size_t)bt * NH + tid] = 1.f / (1.f + expf(-sb));
        float xg = sa + dt_bias[tid];
        float sp = fmaxf(xg, 0.f) + log1pf(expf(-fabsf(xg)));
        g[(size_t)bt * NH + tid] = -expf(A_log[tid]) * sp;
    }
}

// ---------------------------------------------------------------------------
// CHUNK PREP (parallel over all 768 (b,h,chunk)) — unchanged from round 7.
// ---------------------------------------------------------------------------
__global__ __launch_bounds__(256) void chunk_prep(const bf16* __restrict__ qbuf,
                                                  const bf16* __restrict__ kbuf,
                                                  bf16* __restrict__ vbuf,
                                                  bf16* __restrict__ tvbuf,
                                                  const float* __restrict__ gbuf,
                                                  const float* __restrict__ bbuf,
                                                  bf16* __restrict__ Bmat,
                                                  float* __restrict__ scl) {
    __shared__ __align__(16) short Ksh[64 * 256];
    __shared__ __align__(16) short Qsh[64 * 256];   // later: K_T [256][64]
    __shared__ __align__(16) float Ash[64 * 68];    // A, then M (in place)
    __shared__ __align__(16) short Vt[128 * 72];
    __shared__ float Lsh[64], betash[64], lamsh[64], blamsh[64];

    const int blk = blockIdx.x;
    const int c = blk % NCH;
    const int hh = (blk / NCH) % NH;
    const int b = blk / (NCH * NH);
    const int tid = threadIdx.x;
    const int wid = tid >> 6;
    const int lane = tid & 63;
    const int bt0 = b * TT + c * CH;
    const int cid = (b * NH + hh) * NCH + c;

    // stage K,Q (swizzled)
    {
        int r = tid >> 2, c0 = (tid & 3) * 64;
        const uint4* kg = (const uint4*)(kbuf + (size_t)(bt0 + r) * 1536 + hh * 256 + c0);
        const uint4* qg = (const uint4*)(qbuf + (size_t)(bt0 + r) * 1536 + hh * 256 + c0);
#pragma unroll
        for (int j = 0; j < 8; ++j) {
            int byte = ((r * 256 + c0 + j * 8) * 2) ^ ((r & 7) << 4);
            *(uint4*)((char*)Ksh + byte) = kg[j];
            *(uint4*)((char*)Qsh + byte) = qg[j];
        }
    }
    if (tid < 64) {
        float gv = gbuf[(size_t)(bt0 + tid) * NH + hh];
        float bv = bbuf[(size_t)(bt0 + tid) * NH + hh];
        float L = gv;
#pragma unroll
        for (int off = 1; off < 64; off <<= 1) {
            float o = __shfl_up(L, off, 64);
            if (lane >= off) L += o;
        }
        float L63 = __shfl(L, 63, 64);
        float lam = expf(L);
        Lsh[tid] = L; betash[tid] = bv; lamsh[tid] = lam; blamsh[tid] = bv * lam;
        scl[(size_t)cid * SCLN + tid] = expf(L63 - L);
        scl[(size_t)cid * SCLN + 68 + tid] = lam;
        if (tid == 63) scl[(size_t)cid * SCLN + 64] = lam;  // LamC = e^{L63}
    }
    __syncthreads();

    // KK^T and QK^T
    f32x4 akk[4], aqk[4];
#pragma unroll
    for (int n = 0; n < 4; ++n) { akk[n] = f32x4{0,0,0,0}; aqk[n] = f32x4{0,0,0,0}; }
#pragma unroll
    for (int kk = 0; kk < 8; ++kk) {
        bf16x8 aK = lfrag256(Ksh, wid * 16, kk * 32);
        bf16x8 aQ = lfrag256(Qsh, wid * 16, kk * 32);
#pragma unroll
        for (int n = 0; n < 4; ++n) {
            bf16x8 bK = lfrag256(Ksh, n * 16, kk * 32);
            akk[n] = __builtin_amdgcn_mfma_f32_16x16x32_bf16(aK, bK, akk[n], 0, 0, 0);
            aqk[n] = __builtin_amdgcn_mfma_f32_16x16x32_bf16(aQ, bK, aqk[n], 0, 0, 0);
        }
    }
    // A_mat + B_mat (C layout: row=(lane>>4)*4+qi, col=lane&15)
#pragma unroll
    for (int n = 0; n < 4; ++n)
#pragma unroll
        for (int qi = 0; qi < 4; ++qi) {
            int i = wid * 16 + (lane >> 4) * 4 + qi;
            int s = n * 16 + (lane & 15);
            float av = 0.f, bvv = 0.f;
            if (s <= i) {
                float sc2 = expf(Lsh[i] - Lsh[s]);
                if (s < i) av = betash[i] * sc2 * akk[n][qi];
                bvv = sc2 * aqk[n][qi];
            }
            Ash[i * 68 + s] = av;
            Bmat[(size_t)cid * 4096 + i * 64 + s] = __float2bfloat16(bvv);
        }
    __syncthreads();

    // solve M = (I+A)^-1 (wave 0, lane = column)
    if (wid == 0) {
        float mm[64];
        mm[0] = (lane == 0) ? 1.f : 0.f;
#pragma unroll
        for (int t = 1; t < 64; ++t) {
            float a0 = 0.f, a1 = 0.f, a2 = 0.f, a3 = 0.f;
#pragma unroll
            for (int s = 0; s < t; ++s) {
                float Av = Ash[t * 68 + s];
                if ((s & 3) == 0) a0 = fmaf(Av, mm[s], a0);
                else if ((s & 3) == 1) a1 = fmaf(Av, mm[s], a1);
                else if ((s & 3) == 2) a2 = fmaf(Av, mm[s], a2);
                else a3 = fmaf(Av, mm[s], a3);
            }
            mm[t] = ((t == lane) ? 1.f : 0.f) - ((a0 + a1) + (a2 + a3));
        }
#pragma unroll
        for (int t = 0; t < 64; ++t) Ash[t * 68 + lane] = mm[t];
    }
    __syncthreads();

    // Tv = M(bV) in 4 d-quarters of 128
    for (int q = 0; q < 4; ++q) {
        {   // stage V quarter transposed: Vt[d][i]
            int i = tid >> 2, d0 = (tid & 3) * 32;
            const uint4* vg = (const uint4*)(vbuf + (size_t)(bt0 + i) * 3072 + hh * 512 + q * 128 + d0);
#pragma unroll
            for (int jb = 0; jb < 4; ++jb) {
                U4S8 u; u.u = vg[jb];
#pragma unroll
                for (int e = 0; e < 8; ++e)
                    Vt[(d0 + jb * 8 + e) * 72 + i] = (short)u.s[e];
            }
        }
        __syncthreads();
        f32x4 acc[8];
#pragma unroll
        for (int n = 0; n < 8; ++n) acc[n] = f32x4{0,0,0,0};
#pragma unroll
        for (int kk = 0; kk < 2; ++kk) {
            bf16x8 am = mfrag(Ash, betash, wid * 16, kk * 32);
#pragma unroll
            for (int n = 0; n < 8; ++n) {
                bf16x8 bv8 = lfrag72(Vt, n * 16, kk * 32);
                acc[n] = __builtin_amdgcn_mfma_f32_16x16x32_bf16(am, bv8, acc[n], 0, 0, 0);
            }
        }
#pragma unroll
        for (int n = 0; n < 8; ++n)
#pragma unroll
            for (int qi = 0; qi < 4; ++qi) {
                int t = wid * 16 + (lane >> 4) * 4 + qi;
                int d = q * 128 + n * 16 + (lane & 15);
                tvbuf[(size_t)(bt0 + t) * 3072 + hh * 512 + d] = __float2bfloat16(acc[n][qi]);
            }
        __syncthreads();
    }

    // build K_T [256][64] into Qsh (swizzled)
    {
        int j = tid;
        unsigned short rowv[64];
#pragma unroll
        for (int s = 0; s < 64; ++s)
            rowv[s] = *(const unsigned short*)((const char*)Ksh + (((s * 256 + j) * 2) ^ ((s & 7) << 4)));
#pragma unroll
        for (int sb = 0; sb < 8; ++sb) {
            U4S8 u;
#pragma unroll
            for (int e = 0; e < 8; ++e) u.s[e] = rowv[sb * 8 + e];
            *(uint4*)((char*)Qsh + (((j * 64 + sb * 8) * 2) ^ ((j & 7) << 4))) = u.u;
        }
    }
    __syncthreads();

    // Tk = M(b.Lam.K): A = M*blam, B = K_T
    {
        f32x4 acc[16];
#pragma unroll
        for (int n = 0; n < 16; ++n) acc[n] = f32x4{0,0,0,0};
#pragma unroll
        for (int kk = 0; kk < 2; ++kk) {
            bf16x8 am = mfrag(Ash, blamsh, wid * 16, kk * 32);
#pragma unroll
            for (int n = 0; n < 16; ++n) {
                bf16x8 bk = lfrag64(Qsh, n * 16, kk * 32);
                acc[n] = __builtin_amdgcn_mfma_f32_16x16x32_bf16(am, bk, acc[n], 0, 0, 0);
            }
        }
#pragma unroll
        for (int n = 0; n < 16; ++n)
#pragma unroll
            for (int qi = 0; qi < 4; ++qi) {
                int t = wid * 16 + (lane >> 4) * 4 + qi;
                int j = n * 16 + (lane & 15);
                vbuf[(size_t)(bt0 + t) * 3072 + hh * 512 + j] = __float2bfloat16(acc[n][qi]);
            }
    }
    // flush K_T -> global segment layout: row i=j>>2 of chunk, cols 256 + (j&3)*64 + s
    {
        int j = tid;
#pragma unroll
        for (int sb = 0; sb < 8; ++sb) {
            uint4 u = *(uint4*)((char*)Qsh + (((j * 64 + sb * 8) * 2) ^ ((j & 7) << 4)));
            *(uint4*)(vbuf + (size_t)(bt0 + (j >> 2)) * 3072 + hh * 512 + 256 + (j & 3) * 64 + sb * 8) = u;
        }
    }
}

// ---------------------------------------------------------------------------
// CHUNK SCAN v2 — register-only (NO LDS). 384 blocks = 12 bh x 32 slices of
// 16 DV cols; 1 wave/block. S kept as 16 f32 C-tiles [k-rows][d-cols]; every
// B-operand (S, U, eC o U) is built lane-locally from C-tiles via the
// C-tile->B-frag identity (C: row=(lane>>4)*4+qi,col=lane&15 is the lane-
// transpose of B: row=lane&15,k=(lane>>4)*4+{0..3,16..19}).
// Per chunk: P=Tk.S; O=lam_t o (Q.S) + Bmat.U; U=Tv-P; S=lamC*S + KT.(eC o U).
// ---------------------------------------------------------------------------
__global__ __launch_bounds__(64, 1) void chunk_scan2(const bf16* __restrict__ qbuf,
                                                     const bf16* __restrict__ vbuf,
                                                     bf16* __restrict__ tvbuf,
                                                     const bf16* __restrict__ Bmat,
                                                     const float* __restrict__ scl) {
    const int lane = threadIdx.x;
    const int slice = blockIdx.x & 31;
    const int bh = blockIdx.x >> 5;
    const int hh = bh % NH;
    const int b = bh / NH;
    const int dglob0 = hh * 512 + slice * 16;
    const int tlo = (lane >> 4) * 4;   // this lane's row-offset inside a C-tile
    const int dcol = lane & 15;        // this lane's d column inside the tile

    f32x4 S[16];
#pragma unroll
    for (int i = 0; i < 16; ++i) S[i] = f32x4{0.f, 0.f, 0.f, 0.f};

    for (int c = 0; c < NCH; ++c) {
        const int bt0 = b * TT + c * CH;
        const int cid = (b * NH + hh) * NCH + c;
        const float* sc = scl + (size_t)cid * SCLN;
        const float lamC = sc[64];

        // S B-frags (one per 32-wide k window), lane-local cvt from C-tiles
        bf16x8 sfr[8];
#pragma unroll
        for (int kk = 0; kk < 8; ++kk) sfr[kk] = pk8t(S[2 * kk], S[2 * kk + 1]);

        // P = Tk.S ; O = Q.S   (C-tiles: rows t, cols d)
        f32x4 P[4], O[4];
#pragma unroll
        for (int tf = 0; tf < 4; ++tf) { P[tf] = f32x4{0,0,0,0}; O[tf] = f32x4{0,0,0,0}; }
#pragma unroll
        for (int tf = 0; tf < 4; ++tf)
#pragma unroll
            for (int kk = 0; kk < 8; ++kk) {
                bf16x8 aT = gfrag(vbuf + (size_t)bt0 * 3072 + hh * 512, 3072, tf * 16, kk * 32);
                bf16x8 aQ = gfrag(qbuf + (size_t)bt0 * 1536 + hh * 256, 1536, tf * 16, kk * 32);
                P[tf] = __builtin_amdgcn_mfma_f32_16x16x32_bf16(aT, sfr[kk], P[tf], 0, 0, 0);
                O[tf] = __builtin_amdgcn_mfma_f32_16x16x32_bf16(aQ, sfr[kk], O[tf], 0, 0, 0);
            }
        // O *= lam_t ; U = Tv - P (in place over P)
#pragma unroll
        for (int tf = 0; tf < 4; ++tf) {
            float4 lam4 = *(const float4*)(sc + 68 + tf * 16 + tlo);
            O[tf][0] *= lam4.x; O[tf][1] *= lam4.y; O[tf][2] *= lam4.z; O[tf][3] *= lam4.w;
            int t = tf * 16 + tlo;
#pragma unroll
            for (int qi = 0; qi < 4; ++qi) {
                float tv = __bfloat162float(tvbuf[(size_t)(bt0 + t + qi) * 3072 + dglob0 + dcol]);
                P[tf][qi] = tv - P[tf][qi];
            }
        }
        // U B-frags, and O += Bmat.U ; store O over Tv slice
        bf16x8 ufr0 = pk8t(P[0], P[1]);
        bf16x8 ufr1 = pk8t(P[2], P[3]);
#pragma unroll
        for (int tf = 0; tf < 4; ++tf) {
            bf16x8 aB0 = gfrag(Bmat + (size_t)cid * 4096, 64, tf * 16, 0);
            bf16x8 aB1 = gfrag(Bmat + (size_t)cid * 4096, 64, tf * 16, 32);
            O[tf] = __builtin_amdgcn_mfma_f32_16x16x32_bf16(aB0, ufr0, O[tf], 0, 0, 0);
            O[tf] = __builtin_amdgcn_mfma_f32_16x16x32_bf16(aB1, ufr1, O[tf], 0, 0, 0);
            int t = tf * 16 + tlo;
#pragma unroll
            for (int qi = 0; qi < 4; ++qi)
                tvbuf[(size_t)(bt0 + t + qi) * 3072 + dglob0 + dcol] = __float2bfloat16(O[tf][qi]);
        }
        // Ut B-frags: eC_t o U, lane-local scale then pack
        bf16x8 utfr[2];
#pragma unroll
        for (int k2 = 0; k2 < 2; ++k2) {
            float4 e0 = *(const float4*)(sc + k2 * 32 + tlo);
            float4 e1 = *(const float4*)(sc + k2 * 32 + 16 + tlo);
            f32x4 ua = P[2 * k2], ub = P[2 * k2 + 1];
            ua[0] *= e0.x; ua[1] *= e0.y; ua[2] *= e0.z; ua[3] *= e0.w;
            ub[0] *= e1.x; ub[1] *= e1.y; ub[2] *= e1.z; ub[3] *= e1.w;
            utfr[k2] = pk8t(ua, ub);
        }
        // S = lamC*S + KT.(eC o U)
#pragma unroll
        for (int kt = 0; kt < 16; ++kt) {
            S[kt][0] *= lamC; S[kt][1] *= lamC; S[kt][2] *= lamC; S[kt][3] *= lamC;
        }
#pragma unroll
        for (int kt = 0; kt < 16; ++kt)
#pragma unroll
            for (int k2 = 0; k2 < 2; ++k2) {
                int j = kt * 16 + dcol;   // K_T row (k index)
                const bf16* kp = vbuf + (size_t)(bt0 + (j >> 2)) * 3072 + hh * 512 + 256 +
                                 (j & 3) * 64 + k2 * 32 + tlo;
                FragU f;
                f.u2[0] = *(const uint2*)kp;
                f.u2[1] = *(const uint2*)(kp + 16);
                S[kt] = __builtin_amdgcn_mfma_f32_16x16x32_bf16(f.v, utfr[k2], S[kt], 0, 0, 0);
            }
    }
}

// ---------------------------------------------------------------------------
// per-head RMSNorm (eps 1e-5) * norm_w, then * silu(gate). In-place (bf16).
// ---------------------------------------------------------------------------
__global__ __launch_bounds__(256) void rmsgate_kernel(bf16* __restrict__ o,
                                                      const bf16* __restrict__ gate,
                                                      const float* __restrict__ norm_w) {
    const int bhead = blockIdx.x;
    const int d = threadIdx.x;
    bf16* op = o + (size_t)bhead * DVv;
    const bf16* gp = gate + (size_t)bhead * DVv;
    float x0 = __bfloat162float(op[d]), x1 = __bfloat162float(op[d + 256]);
    float s = x0 * x0 + x1 * x1;
#pragma unroll
    for (int off = 32; off >= 1; off >>= 1) s += __shfl_down(s, off, 64);
    __shared__ float red[4];
    if ((threadIdx.x & 63) == 0) red[threadIdx.x >> 6] = s;
    __syncthreads();
    float tot = (red[0] + red[1]) + (red[2] + red[3]);
    float r = rsqrtf(tot * (1.f / DVv) + 1e-5f);
    float g0 = __bfloat162float(gp[d]), g1 = __bfloat162float(gp[d + 256]);
    g0 = g0 / (1.f + expf(-g0));
    g1 = g1 / (1.f + expf(-g1));
    op[d]       = __float2bfloat16(x0 * r * norm_w[d] * g0);
    op[d + 256] = __float2bfloat16(x1 * r * norm_w[d + 256] * g1);
}

__global__ void fill_kernel(float* p, int n, float v) {
    int i = blockIdx.x * 256 + threadIdx.x;
    if (i < n) p[i] = v;
}

// ---------------------------------------------------------------------------
extern "C" void kernel_launch(void* const* d_in, const int* in_sizes, int n_in,
                              void* d_out, int out_size, void* d_ws, size_t ws_size,
                              hipStream_t stream) {
    const float* x       = (const float*)d_in[0];
    const float* Wq      = (const float*)d_in[1];
    const float* Wk      = (const float*)d_in[2];
    const float* Wv      = (const float*)d_in[3];
    const float* Wb      = (const float*)d_in[4];
    const float* Wa      = (const float*)d_in[5];
    const float* A_log   = (const float*)d_in[6];
    const float* dt_bias = (const float*)d_in[7];
    const float* cwq     = (const float*)d_in[8];
    const float* cwk     = (const float*)d_in[9];
    const float* cwv     = (const float*)d_in[10];
    const float* Wg      = (const float*)d_in[11];
    const float* norm_w  = (const float*)d_in[12];
    const float* Wo      = (const float*)d_in[13];
    float* out = (float*)d_out;

    // d_out scratch: qb/kb ONLY (write-once-read-later, replay-proven).
    bf16* qb = (bf16*)d_out;                          // [8192,1536]
    bf16* kb = qb + (size_t)MTOK * 1536;              // [8192,1536]

    // ws: A = {preQ|preK | v -> Tk/K_T | gate}, B = {preV | Tv -> O},
    //     Bmat, scl, beta, g.
    const size_t elemsA = (size_t)MTOK * 3072;
    const size_t elemsB = (size_t)MTOK * 3072;
    bf16* wsA   = (bf16*)d_ws;
    bf16* wsB   = wsA + elemsA;
    bf16* Bmat  = wsB + elemsB;                       // [768][64][64]
    float* scl  = (float*)(Bmat + (size_t)NBb * NH * NCH * 4096);  // [768][136]
    float* betab = scl + (size_t)NBb * NH * NCH * SCLN;
    float* gb    = betab + (size_t)MTOK * NH;
    size_t need = ((size_t)(gb - (float*)d_ws) + (size_t)MTOK * NH) * sizeof(float);
    if (ws_size < need) {
        fill_kernel<<<(out_size + 255) / 256, 256, 0, stream>>>(out, out_size, 1e9f);
        return;
    }

    dim3 blk(256);
    // q projection -> conv+silu+l2norm (*DK^-0.5)
    mfma_gemm_nt<float, bf16><<<dim3(12, 64), blk, 0, stream>>>(x, Wq, wsA, MTOK, 1536, HIDDIM);
    convnorm_qk<<<MTOK * NH, dim3(DKk), 0, stream>>>(wsA, cwq, qb, 0.0625f);
    // k projection -> conv+silu+l2norm
    mfma_gemm_nt<float, bf16><<<dim3(12, 64), blk, 0, stream>>>(x, Wk, wsA, MTOK, 1536, HIDDIM);
    convnorm_qk<<<MTOK * NH, dim3(DKk), 0, stream>>>(wsA, cwk, kb, 1.0f);
    // v projection (into B) -> conv+silu (into A)
    mfma_gemm_nt<float, bf16><<<dim3(24, 64), blk, 0, stream>>>(x, Wv, wsB, MTOK, 3072, HIDDIM);
    conv_v_kernel<<<(MTOK * 3072) / 256, blk, 0, stream>>>(wsB, cwv, wsA);
    // beta / g
    proj_ab<<<MTOK, blk, 0, stream>>>(x, Wb, Wa, A_log, dt_bias, betab, gb);
    // chunked delta rule: prep (parallel) + scan v2 (register-only)
    chunk_prep<<<NBb * NH * NCH, blk, 0, stream>>>(qb, kb, wsA, wsB, gb, betab, Bmat, scl);
    chunk_scan2<<<NBb * NH * 32, dim3(64), 0, stream>>>(qb, wsA, wsB, Bmat, scl);
    // gate projection into A (Tk/K_T dead after scan)
    mfma_gemm_nt<float, bf16><<<dim3(24, 64), blk, 0, stream>>>(x, Wg, wsA, MTOK, 3072, HIDDIM);
    // rmsnorm + silu(gate), in place on O (wsB)
    rmsgate_kernel<<<MTOK * NH, blk, 0, stream>>>(wsB, wsA, norm_w);
    // output projection: O (bf16, wsB) x Wo (fp32) -> d_out fp32
    mfma_gemm_nt<bf16, float><<<dim3(16, 64), blk, 0, stream>>>(wsB, Wo, out, MTOK, 2048, 3072);
}

// Round 9
// 2960.883 us; speedup vs baseline: 28.9441x; 1.1888x over previous
//
#include <hip/hip_runtime.h>
#include <hip/hip_bf16.h>
#include <math.h>

#define NH 6
#define DKk 256
#define DVv 512
#define HIDDIM 2048
#define TT 4096
#define NBb 2
#define MTOK (NBb*TT)   // 8192
#define CH 64
#define NCH (TT/CH)     // 64 chunks per sequence
#define SCLN 136

typedef __hip_bfloat16 bf16;
typedef __attribute__((ext_vector_type(8))) short bf16x8;
typedef __attribute__((ext_vector_type(4))) float f32x4;

union FragU { bf16x8 v; uint2 u2[2]; uint4 u4; };
union BfBits { bf16 h; unsigned short s; };
union U4S8 { uint4 u; unsigned short s[8]; };

__device__ inline float bflo(unsigned u) { return __uint_as_float(u << 16); }
__device__ inline float bfhi(unsigned u) { return __uint_as_float(u & 0xffff0000u); }
__device__ inline unsigned short bfbits(float f) {
    BfBits b; b.h = __float2bfloat16(f); return b.s;
}
__device__ inline float bf2f(unsigned short s) { return __uint_as_float(((unsigned)s) << 16); }
__device__ inline uint4 pack8(float4 a, float4 b) {
    U4S8 r;
    r.s[0] = bfbits(a.x); r.s[1] = bfbits(a.y); r.s[2] = bfbits(a.z); r.s[3] = bfbits(a.w);
    r.s[4] = bfbits(b.x); r.s[5] = bfbits(b.y); r.s[6] = bfbits(b.z); r.s[7] = bfbits(b.w);
    return r.u;
}
__device__ inline uint2 packh4(float a, float b, float c, float d) {
    union { unsigned short s[4]; uint2 u; } r;
    r.s[0] = bfbits(a); r.s[1] = bfbits(b); r.s[2] = bfbits(c); r.s[3] = bfbits(d);
    return r.u;
}
// pack two f32x4 C-tiles (same lane) into a bf16x8 B-frag (C-tile->B-frag identity)
__device__ inline bf16x8 pk8t(f32x4 a, f32x4 b) {
    U4S8 r;
    r.s[0] = bfbits(a[0]); r.s[1] = bfbits(a[1]); r.s[2] = bfbits(a[2]); r.s[3] = bfbits(a[3]);
    r.s[4] = bfbits(b[0]); r.s[5] = bfbits(b[1]); r.s[6] = bfbits(b[2]); r.s[7] = bfbits(b[3]);
    FragU f; f.u4 = r.u; return f.v;
}

// A/B-fragment loader from global. lane: row = n0+(lane&15),
// k = k0+(lane>>4)*4+{0..3} and +16+{0..3} (consistent across all operands).
__device__ inline bf16x8 gfrag(const bf16* base, size_t stride, int n0, int k0) {
    int lane = threadIdx.x & 63;
    const bf16* p = base + (size_t)(n0 + (lane & 15)) * stride + k0 + ((lane >> 4) * 4);
    FragU f; f.u2[0] = *(const uint2*)p; f.u2[1] = *(const uint2*)(p + 16);
    return f.v;
}
// LDS tile stride 256 elems, XOR-swizzled by ((row&7)<<4) on byte offset
__device__ inline bf16x8 lfrag256(const short* sh, int n0, int k0) {
    int lane = threadIdx.x & 63;
    int r = n0 + (lane & 15);
    int c = k0 + ((lane >> 4) * 4);
    FragU f;
    f.u2[0] = *(const uint2*)((const char*)sh + (((r * 256 + c) * 2) ^ ((r & 7) << 4)));
    f.u2[1] = *(const uint2*)((const char*)sh + (((r * 256 + c + 16) * 2) ^ ((r & 7) << 4)));
    return f.v;
}
// LDS tile stride 64 elems, swizzled
__device__ inline bf16x8 lfrag64(const short* sh, int n0, int k0) {
    int lane = threadIdx.x & 63;
    int r = n0 + (lane & 15);
    int c = k0 + ((lane >> 4) * 4);
    FragU f;
    f.u2[0] = *(const uint2*)((const char*)sh + (((r * 64 + c) * 2) ^ ((r & 7) << 4)));
    f.u2[1] = *(const uint2*)((const char*)sh + (((r * 64 + c + 16) * 2) ^ ((r & 7) << 4)));
    return f.v;
}
// LDS tile stride 72 elems (padded), no swizzle
__device__ inline bf16x8 lfrag72(const short* sh, int n0, int k0) {
    int lane = threadIdx.x & 63;
    int r = n0 + (lane & 15);
    int c = k0 + ((lane >> 4) * 4);
    FragU f;
    f.u2[0] = *(const uint2*)((const char*)sh + (r * 72 + c) * 2);
    f.u2[1] = *(const uint2*)((const char*)sh + (r * 72 + c + 16) * 2);
    return f.v;
}
// A-frag from f32 [64][68] LDS, scaled per-column, cvt to bf16
__device__ inline bf16x8 mfrag(const float* Msh, const float* colscale, int m0, int k0) {
    int lane = threadIdx.x & 63;
    int t = m0 + (lane & 15);
    int s0 = k0 + ((lane >> 4) * 4);
    U4S8 r;
#pragma unroll
    for (int i = 0; i < 4; ++i) {
        r.s[i]     = bfbits(Msh[t * 68 + s0 + i]      * colscale[s0 + i]);
        r.s[4 + i] = bfbits(Msh[t * 68 + s0 + 16 + i] * colscale[s0 + 16 + i]);
    }
    FragU f; f.u4 = r.u; return f.v;
}

// ---------------------------------------------------------------------------
// MFMA GEMM: C[m,n] = sum_k A[m,k]*B[n,k]; A: [M,K] (fp32 or bf16), B: [N,K]
// fp32. bf16 MFMA 16x16x32, fp32 accum. Tile 128x128xBK64, 4 waves.
// ---------------------------------------------------------------------------
template <typename TA, typename TC>
__global__ __launch_bounds__(256) void mfma_gemm_nt(const TA* __restrict__ A,
                                                    const float* __restrict__ B,
                                                    TC* __restrict__ C,
                                                    int M, int N, int K) {
    __shared__ __align__(16) short As[128 * 64];
    __shared__ __align__(16) short Bs[128 * 64];
    const int tid = threadIdx.x;
    const int lane = tid & 63;
    const int wid = tid >> 6;
    const int wr = wid >> 1, wc = wid & 1;
    const int bm = blockIdx.y * 128, bn = blockIdx.x * 128;
    const int srow = tid >> 1;
    const int sks = (tid & 1) * 32;

    f32x4 acc[4][4];
#pragma unroll
    for (int i = 0; i < 4; ++i)
#pragma unroll
        for (int j = 0; j < 4; ++j) acc[i][j] = f32x4{0.f, 0.f, 0.f, 0.f};

    auto swzb = [](int row, int kelem) {
        return ((row * 64 + kelem) * 2) ^ ((row & 7) << 4);
    };
    uint4 ra[4], rb[4];
    auto fetch = [&](int k0) {
        if constexpr (sizeof(TA) == 2) {
            const uint4* pa = (const uint4*)(A + (size_t)(bm + srow) * K + k0 + sks);
#pragma unroll
            for (int j = 0; j < 4; ++j) ra[j] = pa[j];
        } else {
            const float4* pa = (const float4*)(A + (size_t)(bm + srow) * K + k0 + sks);
#pragma unroll
            for (int j = 0; j < 4; ++j) ra[j] = pack8(pa[2 * j], pa[2 * j + 1]);
        }
        const float4* pb = (const float4*)(B + (size_t)(bn + srow) * K + k0 + sks);
#pragma unroll
        for (int j = 0; j < 4; ++j) rb[j] = pack8(pb[2 * j], pb[2 * j + 1]);
    };
    auto store_lds = [&]() {
#pragma unroll
        for (int j = 0; j < 4; ++j) {
            int byte = swzb(srow, sks + 8 * j);
            *(uint4*)((char*)As + byte) = ra[j];
            *(uint4*)((char*)Bs + byte) = rb[j];
        }
    };
    auto rdfrag = [&](const short* Sm, int row, int kbase) {
        FragU f;
        int ko = kbase + (lane >> 4) * 4;
        f.u2[0] = *(const uint2*)((const char*)Sm + swzb(row, ko));
        f.u2[1] = *(const uint2*)((const char*)Sm + swzb(row, ko + 16));
        return f.v;
    };

    fetch(0);
    for (int k0 = 0; k0 < K; k0 += 64) {
        __syncthreads();
        store_lds();
        __syncthreads();
        if (k0 + 64 < K) fetch(k0 + 64);
#pragma unroll
        for (int kk = 0; kk < 2; ++kk) {
            bf16x8 af[4], bfr[4];
#pragma unroll
            for (int i = 0; i < 4; ++i)
                af[i] = rdfrag(As, wr * 64 + i * 16 + (lane & 15), kk * 32);
#pragma unroll
            for (int j = 0; j < 4; ++j)
                bfr[j] = rdfrag(Bs, wc * 64 + j * 16 + (lane & 15), kk * 32);
#pragma unroll
            for (int i = 0; i < 4; ++i)
#pragma unroll
                for (int j = 0; j < 4; ++j)
                    acc[i][j] = __builtin_amdgcn_mfma_f32_16x16x32_bf16(
                        af[i], bfr[j], acc[i][j], 0, 0, 0);
        }
    }
#pragma unroll
    for (int i = 0; i < 4; ++i)
#pragma unroll
        for (int j = 0; j < 4; ++j) {
            int row = bm + wr * 64 + i * 16 + (lane >> 4) * 4;
            int col = bn + wc * 64 + j * 16 + (lane & 15);
#pragma unroll
            for (int qi = 0; qi < 4; ++qi) {
                float vv = acc[i][j][qi];
                if constexpr (sizeof(TC) == 2)
                    C[(size_t)(row + qi) * N + col] = __float2bfloat16(vv);
                else
                    C[(size_t)(row + qi) * N + col] = vv;
            }
        }
}

// ---------------------------------------------------------------------------
// causal depthwise conv4 + SiLU + per-head l2norm (+scale) for q/k.
// ---------------------------------------------------------------------------
__global__ __launch_bounds__(256) void convnorm_qk(const bf16* __restrict__ pre,
                                                   const float* __restrict__ cw,
                                                   bf16* __restrict__ out,
                                                   float scale) {
    const int bth = blockIdx.x;
    const int h = bth % NH;
    const int bt = bth / NH;
    const int t = bt % TT;
    const int d = threadIdx.x;
    const int c = h * DKk + d;
    const int C = NH * DKk;
    const bf16* p = pre + (size_t)bt * C + c;

    float w0 = cw[c * 4 + 0], w1 = cw[c * 4 + 1], w2 = cw[c * 4 + 2], w3 = cw[c * 4 + 3];
    float y = w3 * __bfloat162float(p[0]);
    if (t >= 1) y = fmaf(w2, __bfloat162float(p[-(ptrdiff_t)C]), y);
    if (t >= 2) y = fmaf(w1, __bfloat162float(p[-(ptrdiff_t)(2 * C)]), y);
    if (t >= 3) y = fmaf(w0, __bfloat162float(p[-(ptrdiff_t)(3 * C)]), y);
    y = y / (1.f + expf(-y));   // SiLU

    float s = y * y;
#pragma unroll
    for (int off = 32; off >= 1; off >>= 1) s += __shfl_down(s, off, 64);
    __shared__ float red[4];
    if ((threadIdx.x & 63) == 0) red[threadIdx.x >> 6] = s;
    __syncthreads();
    float tot = (red[0] + red[1]) + (red[2] + red[3]);
    out[(size_t)bt * C + c] = __float2bfloat16(y * rsqrtf(tot + 1e-6f) * scale);
}

// ---------------------------------------------------------------------------
// causal depthwise conv4 + SiLU for v.
// ---------------------------------------------------------------------------
__global__ __launch_bounds__(256) void conv_v_kernel(const bf16* __restrict__ pre,
                                                     const float* __restrict__ cw,
                                                     bf16* __restrict__ out) {
    const int C = NH * DVv;
    int idx = blockIdx.x * 256 + threadIdx.x;
    int c = idx % C;
    int bt = idx / C;
    int t = bt % TT;
    const bf16* p = pre + (size_t)bt * C + c;
    float y = cw[c * 4 + 3] * __bfloat162float(p[0]);
    if (t >= 1) y = fmaf(cw[c * 4 + 2], __bfloat162float(p[-(ptrdiff_t)C]), y);
    if (t >= 2) y = fmaf(cw[c * 4 + 1], __bfloat162float(p[-(ptrdiff_t)(2 * C)]), y);
    if (t >= 3) y = fmaf(cw[c * 4 + 0], __bfloat162float(p[-(ptrdiff_t)(3 * C)]), y);
    out[(size_t)bt * C + c] = __float2bfloat16(y / (1.f + expf(-y)));
}

// ---------------------------------------------------------------------------
// beta = sigmoid(x@Wb.T), g = -exp(A_log)*softplus(x@Wa.T + dt_bias)
// ---------------------------------------------------------------------------
__global__ __launch_bounds__(256) void proj_ab(const float* __restrict__ x,
                                               const float* __restrict__ Wb,
                                               const float* __restrict__ Wa,
                                               const float* __restrict__ A_log,
                                               const float* __restrict__ dt_bias,
                                               float* __restrict__ beta,
                                               float* __restrict__ g) {
    const int bt = blockIdx.x;
    const int tid = threadIdx.x;
    const float* xr = x + (size_t)bt * HIDDIM;
    float accb[NH], acca[NH];
#pragma unroll
    for (int h = 0; h < NH; ++h) { accb[h] = 0.f; acca[h] = 0.f; }
    for (int k0 = tid; k0 < HIDDIM; k0 += 256) {
        float xv = xr[k0];
#pragma unroll
        for (int h = 0; h < NH; ++h) {
            accb[h] = fmaf(xv, Wb[h * HIDDIM + k0], accb[h]);
            acca[h] = fmaf(xv, Wa[h * HIDDIM + k0], acca[h]);
        }
    }
#pragma unroll
    for (int h = 0; h < NH; ++h) {
#pragma unroll
        for (int off = 32; off >= 1; off >>= 1) {
            accb[h] += __shfl_down(accb[h], off, 64);
            acca[h] += __shfl_down(acca[h], off, 64);
        }
    }
    __shared__ float redb[NH][4], reda[NH][4];
    int wv = tid >> 6;
    if ((tid & 63) == 0) {
#pragma unroll
        for (int h = 0; h < NH; ++h) { redb[h][wv] = accb[h]; reda[h][wv] = acca[h]; }
    }
    __syncthreads();
    if (tid < NH) {
        float sb = (redb[tid][0] + redb[tid][1]) + (redb[tid][2] + redb[tid][3]);
        float sa = (reda[tid][0] + reda[tid][1]) + (reda[tid][2] + reda[tid][3]);
        beta[(size_t)bt * NH + tid] = 1.f / (1.f + expf(-sb));
        float xg = sa + dt_bias[tid];
        float sp = fmaxf(xg, 0.f) + log1pf(expf(-fabsf(xg)));
        g[(size_t)bt * NH + tid] = -expf(A_log[tid]) * sp;
    }
}

// ---------------------------------------------------------------------------
// CHUNK PREP (parallel over all 768 (b,h,chunk)) — unchanged.
// ---------------------------------------------------------------------------
__global__ __launch_bounds__(256) void chunk_prep(const bf16* __restrict__ qbuf,
                                                  const bf16* __restrict__ kbuf,
                                                  bf16* __restrict__ vbuf,
                                                  bf16* __restrict__ tvbuf,
                                                  const float* __restrict__ gbuf,
                                                  const float* __restrict__ bbuf,
                                                  bf16* __restrict__ Bmat,
                                                  float* __restrict__ scl) {
    __shared__ __align__(16) short Ksh[64 * 256];
    __shared__ __align__(16) short Qsh[64 * 256];   // later: K_T [256][64]
    __shared__ __align__(16) float Ash[64 * 68];    // A, then M (in place)
    __shared__ __align__(16) short Vt[128 * 72];
    __shared__ float Lsh[64], betash[64], lamsh[64], blamsh[64];

    const int blk = blockIdx.x;
    const int c = blk % NCH;
    const int hh = (blk / NCH) % NH;
    const int b = blk / (NCH * NH);
    const int tid = threadIdx.x;
    const int wid = tid >> 6;
    const int lane = tid & 63;
    const int bt0 = b * TT + c * CH;
    const int cid = (b * NH + hh) * NCH + c;

    // stage K,Q (swizzled)
    {
        int r = tid >> 2, c0 = (tid & 3) * 64;
        const uint4* kg = (const uint4*)(kbuf + (size_t)(bt0 + r) * 1536 + hh * 256 + c0);
        const uint4* qg = (const uint4*)(qbuf + (size_t)(bt0 + r) * 1536 + hh * 256 + c0);
#pragma unroll
        for (int j = 0; j < 8; ++j) {
            int byte = ((r * 256 + c0 + j * 8) * 2) ^ ((r & 7) << 4);
            *(uint4*)((char*)Ksh + byte) = kg[j];
            *(uint4*)((char*)Qsh + byte) = qg[j];
        }
    }
    if (tid < 64) {
        float gv = gbuf[(size_t)(bt0 + tid) * NH + hh];
        float bv = bbuf[(size_t)(bt0 + tid) * NH + hh];
        float L = gv;
#pragma unroll
        for (int off = 1; off < 64; off <<= 1) {
            float o = __shfl_up(L, off, 64);
            if (lane >= off) L += o;
        }
        float L63 = __shfl(L, 63, 64);
        float lam = expf(L);
        Lsh[tid] = L; betash[tid] = bv; lamsh[tid] = lam; blamsh[tid] = bv * lam;
        scl[(size_t)cid * SCLN + tid] = expf(L63 - L);
        scl[(size_t)cid * SCLN + 68 + tid] = lam;
        if (tid == 63) scl[(size_t)cid * SCLN + 64] = lam;  // LamC = e^{L63}
    }
    __syncthreads();

    // KK^T and QK^T
    f32x4 akk[4], aqk[4];
#pragma unroll
    for (int n = 0; n < 4; ++n) { akk[n] = f32x4{0,0,0,0}; aqk[n] = f32x4{0,0,0,0}; }
#pragma unroll
    for (int kk = 0; kk < 8; ++kk) {
        bf16x8 aK = lfrag256(Ksh, wid * 16, kk * 32);
        bf16x8 aQ = lfrag256(Qsh, wid * 16, kk * 32);
#pragma unroll
        for (int n = 0; n < 4; ++n) {
            bf16x8 bK = lfrag256(Ksh, n * 16, kk * 32);
            akk[n] = __builtin_amdgcn_mfma_f32_16x16x32_bf16(aK, bK, akk[n], 0, 0, 0);
            aqk[n] = __builtin_amdgcn_mfma_f32_16x16x32_bf16(aQ, bK, aqk[n], 0, 0, 0);
        }
    }
    // A_mat + B_mat (C layout: row=(lane>>4)*4+qi, col=lane&15)
#pragma unroll
    for (int n = 0; n < 4; ++n)
#pragma unroll
        for (int qi = 0; qi < 4; ++qi) {
            int i = wid * 16 + (lane >> 4) * 4 + qi;
            int s = n * 16 + (lane & 15);
            float av = 0.f, bvv = 0.f;
            if (s <= i) {
                float sc2 = expf(Lsh[i] - Lsh[s]);
                if (s < i) av = betash[i] * sc2 * akk[n][qi];
                bvv = sc2 * aqk[n][qi];
            }
            Ash[i * 68 + s] = av;
            Bmat[(size_t)cid * 4096 + i * 64 + s] = __float2bfloat16(bvv);
        }
    __syncthreads();

    // solve M = (I+A)^-1 (wave 0, lane = column)
    if (wid == 0) {
        float mm[64];
        mm[0] = (lane == 0) ? 1.f : 0.f;
#pragma unroll
        for (int t = 1; t < 64; ++t) {
            float a0 = 0.f, a1 = 0.f, a2 = 0.f, a3 = 0.f;
#pragma unroll
            for (int s = 0; s < t; ++s) {
                float Av = Ash[t * 68 + s];
                if ((s & 3) == 0) a0 = fmaf(Av, mm[s], a0);
                else if ((s & 3) == 1) a1 = fmaf(Av, mm[s], a1);
                else if ((s & 3) == 2) a2 = fmaf(Av, mm[s], a2);
                else a3 = fmaf(Av, mm[s], a3);
            }
            mm[t] = ((t == lane) ? 1.f : 0.f) - ((a0 + a1) + (a2 + a3));
        }
#pragma unroll
        for (int t = 0; t < 64; ++t) Ash[t * 68 + lane] = mm[t];
    }
    __syncthreads();

    // Tv = M(bV) in 4 d-quarters of 128
    for (int q = 0; q < 4; ++q) {
        {   // stage V quarter transposed: Vt[d][i]
            int i = tid >> 2, d0 = (tid & 3) * 32;
            const uint4* vg = (const uint4*)(vbuf + (size_t)(bt0 + i) * 3072 + hh * 512 + q * 128 + d0);
#pragma unroll
            for (int jb = 0; jb < 4; ++jb) {
                U4S8 u; u.u = vg[jb];
#pragma unroll
                for (int e = 0; e < 8; ++e)
                    Vt[(d0 + jb * 8 + e) * 72 + i] = (short)u.s[e];
            }
        }
        __syncthreads();
        f32x4 acc[8];
#pragma unroll
        for (int n = 0; n < 8; ++n) acc[n] = f32x4{0,0,0,0};
#pragma unroll
        for (int kk = 0; kk < 2; ++kk) {
            bf16x8 am = mfrag(Ash, betash, wid * 16, kk * 32);
#pragma unroll
            for (int n = 0; n < 8; ++n) {
                bf16x8 bv8 = lfrag72(Vt, n * 16, kk * 32);
                acc[n] = __builtin_amdgcn_mfma_f32_16x16x32_bf16(am, bv8, acc[n], 0, 0, 0);
            }
        }
#pragma unroll
        for (int n = 0; n < 8; ++n)
#pragma unroll
            for (int qi = 0; qi < 4; ++qi) {
                int t = wid * 16 + (lane >> 4) * 4 + qi;
                int d = q * 128 + n * 16 + (lane & 15);
                tvbuf[(size_t)(bt0 + t) * 3072 + hh * 512 + d] = __float2bfloat16(acc[n][qi]);
            }
        __syncthreads();
    }

    // build K_T [256][64] into Qsh (swizzled)
    {
        int j = tid;
        unsigned short rowv[64];
#pragma unroll
        for (int s = 0; s < 64; ++s)
            rowv[s] = *(const unsigned short*)((const char*)Ksh + (((s * 256 + j) * 2) ^ ((s & 7) << 4)));
#pragma unroll
        for (int sb = 0; sb < 8; ++sb) {
            U4S8 u;
#pragma unroll
            for (int e = 0; e < 8; ++e) u.s[e] = rowv[sb * 8 + e];
            *(uint4*)((char*)Qsh + (((j * 64 + sb * 8) * 2) ^ ((j & 7) << 4))) = u.u;
        }
    }
    __syncthreads();

    // Tk = M(b.Lam.K): A = M*blam, B = K_T
    {
        f32x4 acc[16];
#pragma unroll
        for (int n = 0; n < 16; ++n) acc[n] = f32x4{0,0,0,0};
#pragma unroll
        for (int kk = 0; kk < 2; ++kk) {
            bf16x8 am = mfrag(Ash, blamsh, wid * 16, kk * 32);
#pragma unroll
            for (int n = 0; n < 16; ++n) {
                bf16x8 bk = lfrag64(Qsh, n * 16, kk * 32);
                acc[n] = __builtin_amdgcn_mfma_f32_16x16x32_bf16(am, bk, acc[n], 0, 0, 0);
            }
        }
#pragma unroll
        for (int n = 0; n < 16; ++n)
#pragma unroll
            for (int qi = 0; qi < 4; ++qi) {
                int t = wid * 16 + (lane >> 4) * 4 + qi;
                int j = n * 16 + (lane & 15);
                vbuf[(size_t)(bt0 + t) * 3072 + hh * 512 + j] = __float2bfloat16(acc[n][qi]);
            }
    }
    // flush K_T -> global segment layout: row i=j>>2 of chunk, cols 256 + (j&3)*64 + s
    {
        int j = tid;
#pragma unroll
        for (int sb = 0; sb < 8; ++sb) {
            uint4 u = *(uint4*)((char*)Qsh + (((j * 64 + sb * 8) * 2) ^ ((j & 7) << 4)));
            *(uint4*)(vbuf + (size_t)(bt0 + (j >> 2)) * 3072 + hh * 512 + 256 + (j & 3) * 64 + sb * 8) = u;
        }
    }
}

// ---------------------------------------------------------------------------
// CHUNK SCAN v3 — LDS-staged operands, 8 waves/block.
// 48 blocks = 12 bh x 4 parts; wave w owns slice part*8+w (16 DV cols).
// Per chunk: cooperative stage of Tk/Q/KT/Bmat (104KB) into LDS (swizzled,
// same layout as lfrag256/lfrag64), then per-wave register-only math
// identical to scan v2 (S as f32 C-tiles; C-tile->B-frag identity).
// ---------------------------------------------------------------------------
__global__ __launch_bounds__(512, 1) void chunk_scan3(const bf16* __restrict__ qbuf,
                                                      const bf16* __restrict__ vbuf,
                                                      bf16* __restrict__ tvbuf,
                                                      const bf16* __restrict__ Bmat,
                                                      const float* __restrict__ scl) {
    __shared__ __align__(16) short TkL[64 * 256];   // 32KB, lfrag256 layout
    __shared__ __align__(16) short QL[64 * 256];    // 32KB, lfrag256
    __shared__ __align__(16) short KTL[256 * 64];   // 32KB, lfrag64
    __shared__ __align__(16) short BmL[64 * 64];    // 8KB,  lfrag64
    const int tid = threadIdx.x;
    const int wid = tid >> 6;
    const int lane = tid & 63;
    const int part = blockIdx.x & 3;
    const int bh = blockIdx.x >> 2;
    const int hh = bh % NH;
    const int b = bh / NH;
    const int slice = part * 8 + wid;            // 0..31
    const int dglob0 = hh * 512 + slice * 16;
    const int tlo = (lane >> 4) * 4;
    const int dcol = lane & 15;

    f32x4 S[16];
#pragma unroll
    for (int i = 0; i < 16; ++i) S[i] = f32x4{0.f, 0.f, 0.f, 0.f};

    for (int c = 0; c < NCH; ++c) {
        const int bt0 = b * TT + c * CH;
        const int cid = (b * NH + hh) * NCH + c;
        const float* sc = scl + (size_t)cid * SCLN;
        const float lamC = sc[64];

        __syncthreads();   // prior chunk's LDS reads complete
        // ---- stage Tk (64x256, vbuf cols [0,256)) and Q (64x256, qbuf) ----
        {
            int r = tid >> 3;                    // 0..63
            int bc0 = (tid & 7) * 16;            // 16B lane within 128B group
#pragma unroll
            for (int rd = 0; rd < 4; ++rd) {
                int bc = bc0 + rd * 128;         // byte col in [0,512)
                uint4 tv = *(const uint4*)((const char*)(vbuf) +
                    ((size_t)(bt0 + r) * 3072 + hh * 512) * 2 + bc);
                uint4 qv = *(const uint4*)((const char*)(qbuf) +
                    ((size_t)(bt0 + r) * 1536 + hh * 256) * 2 + bc);
                int byte = (r * 512 + bc) ^ ((r & 7) << 4);
                *(uint4*)((char*)TkL + byte) = tv;
                *(uint4*)((char*)QL + byte) = qv;
            }
        }
        // ---- stage KT (256x64, vbuf cols [256,512) packed) ----
        {
            int j = tid >> 1;                    // 0..255
            int bc0 = (tid & 1) * 16;
#pragma unroll
            for (int rd = 0; rd < 4; ++rd) {
                int bc = bc0 + rd * 32;          // byte col in [0,128)
                uint4 v = *(const uint4*)((const char*)(vbuf) +
                    ((size_t)(bt0 + (j >> 2)) * 3072 + hh * 512 + 256 + (j & 3) * 64) * 2 + bc);
                int byte = (j * 128 + bc) ^ ((j & 7) << 4);
                *(uint4*)((char*)KTL + byte) = v;
            }
        }
        // ---- stage Bmat (64x64) ----
        {
            int r = tid >> 3;
            int bc = (tid & 7) * 16;
            uint4 v = *(const uint4*)((const char*)(Bmat) +
                ((size_t)cid * 4096 + r * 64) * 2 + bc);
            int byte = (r * 128 + bc) ^ ((r & 7) << 4);
            *(uint4*)((char*)BmL + byte) = v;
        }
        __syncthreads();

        // ---- per-wave register-only math (identical to scan v2) ----
        bf16x8 sfr[8];
#pragma unroll
        for (int kk = 0; kk < 8; ++kk) sfr[kk] = pk8t(S[2 * kk], S[2 * kk + 1]);

        f32x4 P[4], O[4];
#pragma unroll
        for (int tf = 0; tf < 4; ++tf) { P[tf] = f32x4{0,0,0,0}; O[tf] = f32x4{0,0,0,0}; }
#pragma unroll
        for (int tf = 0; tf < 4; ++tf)
#pragma unroll
            for (int kk = 0; kk < 8; ++kk) {
                bf16x8 aT = lfrag256(TkL, tf * 16, kk * 32);
                bf16x8 aQ = lfrag256(QL, tf * 16, kk * 32);
                P[tf] = __builtin_amdgcn_mfma_f32_16x16x32_bf16(aT, sfr[kk], P[tf], 0, 0, 0);
                O[tf] = __builtin_amdgcn_mfma_f32_16x16x32_bf16(aQ, sfr[kk], O[tf], 0, 0, 0);
            }
        // O *= lam_t ; U = Tv - P (in place over P)
#pragma unroll
        for (int tf = 0; tf < 4; ++tf) {
            float4 lam4 = *(const float4*)(sc + 68 + tf * 16 + tlo);
            O[tf][0] *= lam4.x; O[tf][1] *= lam4.y; O[tf][2] *= lam4.z; O[tf][3] *= lam4.w;
            int t = tf * 16 + tlo;
#pragma unroll
            for (int qi = 0; qi < 4; ++qi) {
                float tv = __bfloat162float(tvbuf[(size_t)(bt0 + t + qi) * 3072 + dglob0 + dcol]);
                P[tf][qi] = tv - P[tf][qi];
            }
        }
        bf16x8 ufr0 = pk8t(P[0], P[1]);
        bf16x8 ufr1 = pk8t(P[2], P[3]);
#pragma unroll
        for (int tf = 0; tf < 4; ++tf) {
            bf16x8 aB0 = lfrag64(BmL, tf * 16, 0);
            bf16x8 aB1 = lfrag64(BmL, tf * 16, 32);
            O[tf] = __builtin_amdgcn_mfma_f32_16x16x32_bf16(aB0, ufr0, O[tf], 0, 0, 0);
            O[tf] = __builtin_amdgcn_mfma_f32_16x16x32_bf16(aB1, ufr1, O[tf], 0, 0, 0);
            int t = tf * 16 + tlo;
#pragma unroll
            for (int qi = 0; qi < 4; ++qi)
                tvbuf[(size_t)(bt0 + t + qi) * 3072 + dglob0 + dcol] = __float2bfloat16(O[tf][qi]);
        }
        // Ut B-frags: eC_t o U
        bf16x8 utfr[2];
#pragma unroll
        for (int k2 = 0; k2 < 2; ++k2) {
            float4 e0 = *(const float4*)(sc + k2 * 32 + tlo);
            float4 e1 = *(const float4*)(sc + k2 * 32 + 16 + tlo);
            f32x4 ua = P[2 * k2], ub = P[2 * k2 + 1];
            ua[0] *= e0.x; ua[1] *= e0.y; ua[2] *= e0.z; ua[3] *= e0.w;
            ub[0] *= e1.x; ub[1] *= e1.y; ub[2] *= e1.z; ub[3] *= e1.w;
            utfr[k2] = pk8t(ua, ub);
        }
        // S = lamC*S + KT.(eC o U)
#pragma unroll
        for (int kt = 0; kt < 16; ++kt) {
            S[kt][0] *= lamC; S[kt][1] *= lamC; S[kt][2] *= lamC; S[kt][3] *= lamC;
        }
#pragma unroll
        for (int kt = 0; kt < 16; ++kt)
#pragma unroll
            for (int k2 = 0; k2 < 2; ++k2) {
                bf16x8 aK = lfrag64(KTL, kt * 16, k2 * 32);
                S[kt] = __builtin_amdgcn_mfma_f32_16x16x32_bf16(aK, utfr[k2], S[kt], 0, 0, 0);
            }
    }
}

// ---------------------------------------------------------------------------
// per-head RMSNorm (eps 1e-5) * norm_w, then * silu(gate). In-place (bf16).
// ---------------------------------------------------------------------------
__global__ __launch_bounds__(256) void rmsgate_kernel(bf16* __restrict__ o,
                                                      const bf16* __restrict__ gate,
                                                      const float* __restrict__ norm_w) {
    const int bhead = blockIdx.x;
    const int d = threadIdx.x;
    bf16* op = o + (size_t)bhead * DVv;
    const bf16* gp = gate + (size_t)bhead * DVv;
    float x0 = __bfloat162float(op[d]), x1 = __bfloat162float(op[d + 256]);
    float s = x0 * x0 + x1 * x1;
#pragma unroll
    for (int off = 32; off >= 1; off >>= 1) s += __shfl_down(s, off, 64);
    __shared__ float red[4];
    if ((threadIdx.x & 63) == 0) red[threadIdx.x >> 6] = s;
    __syncthreads();
    float tot = (red[0] + red[1]) + (red[2] + red[3]);
    float r = rsqrtf(tot * (1.f / DVv) + 1e-5f);
    float g0 = __bfloat162float(gp[d]), g1 = __bfloat162float(gp[d + 256]);
    g0 = g0 / (1.f + expf(-g0));
    g1 = g1 / (1.f + expf(-g1));
    op[d]       = __float2bfloat16(x0 * r * norm_w[d] * g0);
    op[d + 256] = __float2bfloat16(x1 * r * norm_w[d + 256] * g1);
}

__global__ void fill_kernel(float* p, int n, float v) {
    int i = blockIdx.x * 256 + threadIdx.x;
    if (i < n) p[i] = v;
}

// ---------------------------------------------------------------------------
extern "C" void kernel_launch(void* const* d_in, const int* in_sizes, int n_in,
                              void* d_out, int out_size, void* d_ws, size_t ws_size,
                              hipStream_t stream) {
    const float* x       = (const float*)d_in[0];
    const float* Wq      = (const float*)d_in[1];
    const float* Wk      = (const float*)d_in[2];
    const float* Wv      = (const float*)d_in[3];
    const float* Wb      = (const float*)d_in[4];
    const float* Wa      = (const float*)d_in[5];
    const float* A_log   = (const float*)d_in[6];
    const float* dt_bias = (const float*)d_in[7];
    const float* cwq     = (const float*)d_in[8];
    const float* cwk     = (const float*)d_in[9];
    const float* cwv     = (const float*)d_in[10];
    const float* Wg      = (const float*)d_in[11];
    const float* norm_w  = (const float*)d_in[12];
    const float* Wo      = (const float*)d_in[13];
    float* out = (float*)d_out;

    // d_out scratch: qb/kb ONLY (write-once-read-later, replay-proven).
    bf16* qb = (bf16*)d_out;                          // [8192,1536]
    bf16* kb = qb + (size_t)MTOK * 1536;              // [8192,1536]

    // ws: A = {preQ|preK | v -> Tk/K_T | gate}, B = {preV | Tv -> O},
    //     Bmat, scl, beta, g.
    const size_t elemsA = (size_t)MTOK * 3072;
    const size_t elemsB = (size_t)MTOK * 3072;
    bf16* wsA   = (bf16*)d_ws;
    bf16* wsB   = wsA + elemsA;
    bf16* Bmat  = wsB + elemsB;                       // [768][64][64]
    float* scl  = (float*)(Bmat + (size_t)NBb * NH * NCH * 4096);  // [768][136]
    float* betab = scl + (size_t)NBb * NH * NCH * SCLN;
    float* gb    = betab + (size_t)MTOK * NH;
    size_t need = ((size_t)(gb - (float*)d_ws) + (size_t)MTOK * NH) * sizeof(float);
    if (ws_size < need) {
        fill_kernel<<<(out_size + 255) / 256, 256, 0, stream>>>(out, out_size, 1e9f);
        return;
    }

    dim3 blk(256);
    // q projection -> conv+silu+l2norm (*DK^-0.5)
    mfma_gemm_nt<float, bf16><<<dim3(12, 64), blk, 0, stream>>>(x, Wq, wsA, MTOK, 1536, HIDDIM);
    convnorm_qk<<<MTOK * NH, dim3(DKk), 0, stream>>>(wsA, cwq, qb, 0.0625f);
    // k projection -> conv+silu+l2norm
    mfma_gemm_nt<float, bf16><<<dim3(12, 64), blk, 0, stream>>>(x, Wk, wsA, MTOK, 1536, HIDDIM);
    convnorm_qk<<<MTOK * NH, dim3(DKk), 0, stream>>>(wsA, cwk, kb, 1.0f);
    // v projection (into B) -> conv+silu (into A)
    mfma_gemm_nt<float, bf16><<<dim3(24, 64), blk, 0, stream>>>(x, Wv, wsB, MTOK, 3072, HIDDIM);
    conv_v_kernel<<<(MTOK * 3072) / 256, blk, 0, stream>>>(wsB, cwv, wsA);
    // beta / g
    proj_ab<<<MTOK, blk, 0, stream>>>(x, Wb, Wa, A_log, dt_bias, betab, gb);
    // chunked delta rule: prep (parallel) + scan v3 (LDS-staged, 8 waves)
    chunk_prep<<<NBb * NH * NCH, blk, 0, stream>>>(qb, kb, wsA, wsB, gb, betab, Bmat, scl);
    chunk_scan3<<<NBb * NH * 4, dim3(512), 0, stream>>>(qb, wsA, wsB, Bmat, scl);
    // gate projection into A (Tk/K_T dead after scan)
    mfma_gemm_nt<float, bf16><<<dim3(24, 64), blk, 0, stream>>>(x, Wg, wsA, MTOK, 3072, HIDDIM);
    // rmsnorm + silu(gate), in place on O (wsB)
    rmsgate_kernel<<<MTOK * NH, blk, 0, stream>>>(wsB, wsA, norm_w);
    // output projection: O (bf16, wsB) x Wo (fp32) -> d_out fp32
    mfma_gemm_nt<bf16, float><<<dim3(16, 64), blk, 0, stream>>>(wsB, Wo, out, MTOK, 2048, 3072);
}